// Round 1
// baseline (4749.818 us; speedup 1.0000x reference)
//
#include <hip/hip_runtime.h>
#include <math.h>

#define EPSV 1e-6f

// ---------------- Kernel 1: LayerNorm(x) over DIM=96 -> xn ----------------
// One wave per token; 262144 tokens; grid 65536 x 256.
__global__ __launch_bounds__(256) void k1_ln1(const float* __restrict__ x,
                                              const float* __restrict__ g,
                                              const float* __restrict__ bta,
                                              float* __restrict__ xn) {
  int wave = threadIdx.x >> 6, lane = threadIdx.x & 63;
  int token = blockIdx.x * 4 + wave;
  const float* xr = x + (size_t)token * 96;
  float v0 = xr[lane];
  float v1 = (lane < 32) ? xr[64 + lane] : 0.f;
  float s = v0 + v1;
#pragma unroll
  for (int o = 32; o; o >>= 1) s += __shfl_xor(s, o);
  float mean = s * (1.f / 96.f);
  float d0 = v0 - mean;
  float d1 = (lane < 32) ? (v1 - mean) : 0.f;
  float q = d0 * d0 + d1 * d1;
#pragma unroll
  for (int o = 32; o; o >>= 1) q += __shfl_xor(q, o);
  float rstd = rsqrtf(q * (1.f / 96.f) + EPSV);
  float* xo = xn + (size_t)token * 96;
  xo[lane] = d0 * rstd * g[lane] + bta[lane];
  if (lane < 32) xo[64 + lane] = d1 * rstd * g[64 + lane] + bta[64 + lane];
}

// ------- Kernel 2: shortcut = maxpool2x2(xn @ proj_w + proj_b) -> d_out ---
// 8 pooled pixels (one row segment) per block; 192 threads = one channel each.
__global__ __launch_bounds__(192) void k2_proj_pool(const float* __restrict__ xn,
                                                    const float* __restrict__ pw,
                                                    const float* __restrict__ pb,
                                                    float* __restrict__ out) {
  __shared__ float sx[2][16][96];  // [row][col][k] source tokens
  int tid = threadIdx.x;
  int pixbase = blockIdx.x * 8;           // flat pooled pixel base
  int b = pixbase >> 14;                  // /(128*128)
  int rem = pixbase & 16383;
  int hp = rem >> 7;
  int wpb = rem & 127;                    // multiple of 8
  int r0 = hp * 2, c0 = wpb * 2;
  // cooperative load: 2 rows x 16 cols x 96 = 3072 floats, contiguous per row
  for (int i = 0; i < 16; ++i) {
    int idx = i * 192 + tid;
    int rr = idx / 1536;
    int r2 = idx - rr * 1536;
    const float* gp = xn + ((size_t)((b * 256 + r0 + rr) * 256 + c0)) * 96;
    ((float*)sx[rr])[r2] = gp[r2];
  }
  __syncthreads();
  int c = tid;
  float acc[8][4];
#pragma unroll
  for (int p = 0; p < 8; ++p)
#pragma unroll
    for (int s2 = 0; s2 < 4; ++s2) acc[p][s2] = 0.f;
  for (int k = 0; k < 96; ++k) {
    float w = pw[k * 192 + c];
#pragma unroll
    for (int p = 0; p < 8; ++p) {
#pragma unroll
      for (int s2 = 0; s2 < 4; ++s2) {
        acc[p][s2] += sx[s2 >> 1][p * 2 + (s2 & 1)][k] * w;
      }
    }
  }
  float bb = pb[c];
#pragma unroll
  for (int p = 0; p < 8; ++p) {
    float m = fmaxf(fmaxf(acc[p][0], acc[p][1]), fmaxf(acc[p][2], acc[p][3]));
    out[(size_t)(pixbase + p) * 192 + c] = m + bb;
  }
}

// --- Kernel 3: windowed attention (pooled Q) + attn_proj; d_out += attn ---
// One block (256 thr) per window; loop over 3 heads to fit LDS (<64KB).
__global__ __launch_bounds__(256) void k3_attn(const float* __restrict__ xn,
                                               const float* __restrict__ qw,
                                               const float* __restrict__ qb,
                                               const float* __restrict__ aw,
                                               const float* __restrict__ ab,
                                               float* __restrict__ out) {
  __shared__ float kh[64][65];   // keys (one head), +1 pad
  __shared__ float vh[64][65];   // values
  __shared__ float qh[16][65];   // pooled queries
  __shared__ float sc[16][65];   // scores/probs
  __shared__ float ob[16][192];  // attention output (all heads)
  int tid = threadIdx.x;
  int wave = tid >> 6, lane = tid & 63;
  int wi = blockIdx.x;
  int b = wi >> 10, nh = (wi >> 5) & 31, nw = wi & 31;
  int grow0 = nh * 8, gcol0 = nw * 8;

  for (int h = 0; h < 3; ++h) {
    int colq = h * 64 + lane;
    int colk = 192 + h * 64 + lane;
    int colv = 384 + h * 64 + lane;
    // K and V for this head: 64 tokens x 64 dims; wave-uniform token rows
    for (int i = 0; i < 16; ++i) {
      int t = i * 4 + wave;
      int r = t >> 3, cc2 = t & 7;
      const float* xr =
          xn + ((size_t)((b * 256 + grow0 + r) * 256 + gcol0 + cc2)) * 96;
      float aK = qb[colk], aV = qb[colv];
      for (int k = 0; k < 96; ++k) {
        float xv = xr[k];
        aK += xv * qw[k * 576 + colk];
        aV += xv * qw[k * 576 + colv];
      }
      kh[t][lane] = aK;
      vh[t][lane] = aV;
    }
    // pooled Q: max over 2x2 token group of (xw @ Wq + bq)
    for (int i = 0; i < 4; ++i) {
      int p = i * 4 + wave;
      int rq = p >> 2, cq = p & 3;
      float m = -1e30f;
#pragma unroll
      for (int s2 = 0; s2 < 4; ++s2) {
        int r = rq * 2 + (s2 >> 1), cc2 = cq * 2 + (s2 & 1);
        const float* xr =
            xn + ((size_t)((b * 256 + grow0 + r) * 256 + gcol0 + cc2)) * 96;
        float a = qb[colq];
        for (int k = 0; k < 96; ++k) a += xr[k] * qw[k * 576 + colq];
        m = fmaxf(m, a);
      }
      qh[p][lane] = m;
    }
    __syncthreads();
    // scores = 0.125 * qh . kh
    for (int i = 0; i < 4; ++i) {
      int p = i * 4 + wave;
      float a = 0.f;
      for (int d = 0; d < 64; ++d) a += qh[p][d] * kh[lane][d];
      sc[p][lane] = a * 0.125f;
    }
    __syncthreads();
    // softmax over 64 keys; 16 rows handled by threads 0..15
    if (tid < 16) {
      float mx = sc[tid][0];
      for (int t = 1; t < 64; ++t) mx = fmaxf(mx, sc[tid][t]);
      float sm = 0.f;
      for (int t = 0; t < 64; ++t) {
        float e = expf(sc[tid][t] - mx);
        sc[tid][t] = e;
        sm += e;
      }
      float inv = 1.f / sm;
      for (int t = 0; t < 64; ++t) sc[tid][t] *= inv;
    }
    __syncthreads();
    // out = probs @ V ; heads write disjoint channel ranges
    for (int i = 0; i < 4; ++i) {
      int p = i * 4 + wave;
      float a = 0.f;
      for (int t = 0; t < 64; ++t) a += sc[p][t] * vh[t][lane];
      ob[p][h * 64 + lane] = a;
    }
    __syncthreads();  // before next head overwrites kh/vh/qh/sc
  }
  // attn_proj + residual add into d_out (holds shortcut)
  for (int i = 0; i < 12; ++i) {
    int e = i * 256 + tid;
    int p = e / 192, c = e - p * 192;
    float a = ab[c];
    for (int j = 0; j < 192; ++j) a += ob[p][j] * aw[j * 192 + c];
    int hp = nh * 4 + (p >> 2), wp = nw * 4 + (p & 3);
    size_t oi = ((size_t)((b * 128 + hp) * 128 + wp)) * 192 + c;
    out[oi] += a;
  }
}

// ------- Kernel 4: LN2 + MLP (GELU exact) + residual; in-place on d_out ---
// 16 tokens per block so W1/W2 are read once per 16 tokens.
__global__ __launch_bounds__(256) void k4_mlp(float* __restrict__ y,
                                              const float* __restrict__ g,
                                              const float* __restrict__ bt,
                                              const float* __restrict__ w1,
                                              const float* __restrict__ b1,
                                              const float* __restrict__ w2,
                                              const float* __restrict__ b2) {
  __shared__ float yn[16][192];
  __shared__ float hh[16][768];
  int tid = threadIdx.x;
  int wave = tid >> 6, lane = tid & 63;
  size_t tokbase = (size_t)blockIdx.x * 16;
  // LayerNorm per token (one wave per 4 tokens)
  for (int j = 0; j < 4; ++j) {
    int tt = wave * 4 + j;
    const float* yr = y + (tokbase + tt) * 192;
    float v0 = yr[lane], v1 = yr[64 + lane], v2 = yr[128 + lane];
    float s = v0 + v1 + v2;
#pragma unroll
    for (int o = 32; o; o >>= 1) s += __shfl_xor(s, o);
    float mean = s * (1.f / 192.f);
    float d0 = v0 - mean, d1 = v1 - mean, d2 = v2 - mean;
    float q = d0 * d0 + d1 * d1 + d2 * d2;
#pragma unroll
    for (int o = 32; o; o >>= 1) q += __shfl_xor(q, o);
    float rstd = rsqrtf(q * (1.f / 192.f) + EPSV);
    yn[tt][lane] = d0 * rstd * g[lane] + bt[lane];
    yn[tt][64 + lane] = d1 * rstd * g[64 + lane] + bt[64 + lane];
    yn[tt][128 + lane] = d2 * rstd * g[128 + lane] + bt[128 + lane];
  }
  __syncthreads();
  // h = gelu(yn @ W1 + b1): 768 cols, 3 col-sets of 256
  for (int cs = 0; cs < 3; ++cs) {
    int c = cs * 256 + tid;
    float acc[16];
    float bb = b1[c];
#pragma unroll
    for (int t = 0; t < 16; ++t) acc[t] = bb;
    for (int k = 0; k < 192; ++k) {
      float w = w1[k * 768 + c];
#pragma unroll
      for (int t = 0; t < 16; ++t) acc[t] += yn[t][k] * w;
    }
#pragma unroll
    for (int t = 0; t < 16; ++t) {
      float v = acc[t];
      hh[t][c] = 0.5f * v * (1.f + erff(v * 0.70710678118654752f));
    }
  }
  __syncthreads();
  // out = h @ W2 + b2 + y (residual, in place)
  if (tid < 192) {
    int c = tid;
    float acc[16];
    float bb = b2[c];
#pragma unroll
    for (int t = 0; t < 16; ++t) acc[t] = bb;
    for (int k = 0; k < 768; ++k) {
      float w = w2[k * 192 + c];
#pragma unroll
      for (int t = 0; t < 16; ++t) acc[t] += hh[t][k] * w;
    }
#pragma unroll
    for (int t = 0; t < 16; ++t) {
      size_t oi = (tokbase + t) * 192 + c;
      y[oi] += acc[t];
    }
  }
}

extern "C" void kernel_launch(void* const* d_in, const int* in_sizes, int n_in,
                              void* d_out, int out_size, void* d_ws,
                              size_t ws_size, hipStream_t stream) {
  const float* x = (const float*)d_in[0];
  const float* n1g = (const float*)d_in[1];
  const float* n1b = (const float*)d_in[2];
  const float* pw = (const float*)d_in[3];
  const float* pb = (const float*)d_in[4];
  const float* qw = (const float*)d_in[5];
  const float* qb = (const float*)d_in[6];
  const float* aw = (const float*)d_in[7];
  const float* ab = (const float*)d_in[8];
  const float* n2g = (const float*)d_in[9];
  const float* n2b = (const float*)d_in[10];
  const float* w1 = (const float*)d_in[11];
  const float* b1 = (const float*)d_in[12];
  const float* w2 = (const float*)d_in[13];
  const float* b2 = (const float*)d_in[14];
  float* out = (float*)d_out;
  float* xn = (float*)d_ws;  // 4*256*256*96*4 = 100,663,296 bytes

  hipLaunchKernelGGL(k1_ln1, dim3(65536), dim3(256), 0, stream, x, n1g, n1b, xn);
  hipLaunchKernelGGL(k2_proj_pool, dim3(8192), dim3(192), 0, stream, xn, pw, pb, out);
  hipLaunchKernelGGL(k3_attn, dim3(4096), dim3(256), 0, stream, xn, qw, qb, aw, ab, out);
  hipLaunchKernelGGL(k4_mlp, dim3(4096), dim3(256), 0, stream, out, n2g, n2b, w1, b1, w2, b2);
}

// Round 2
// 1576.874 us; speedup vs baseline: 3.0122x; 3.0122x over previous
//
#include <hip/hip_runtime.h>
#include <hip/hip_bf16.h>
#include <math.h>

#define EPSV 1e-6f

typedef __attribute__((ext_vector_type(8))) short bf16x8;
typedef __attribute__((ext_vector_type(4))) float f32x4;
typedef __attribute__((ext_vector_type(4))) unsigned short u16x4;

__device__ inline float bf2f(unsigned short u) {
  union { unsigned int i; float f; } v;
  v.i = ((unsigned int)u) << 16;
  return v.f;
}
__device__ inline unsigned short f2bf(float f) {
  __hip_bfloat16 h = __float2bfloat16(f);  // RNE
  return __builtin_bit_cast(unsigned short, h);
}

// ---- Kernel 0: pack qkv_w (96x576) and attn_proj_w (192x192) into MFMA ----
// B-fragment layout: [ntile][kstep][lane][8] bf16, n=ntile*16+(lane&15),
// k=kstep*32+(lane>>4)*8+j.  qw: 36 ntiles x 3 ksteps; aw: 12 x 6.
__global__ __launch_bounds__(256) void k0_pack(const float* __restrict__ qw,
                                               const float* __restrict__ aw,
                                               unsigned short* __restrict__ qwp,
                                               unsigned short* __restrict__ awp) {
  int idx = blockIdx.x * 256 + threadIdx.x;
  if (idx < 6912) {  // 108 frags * 64 lanes
    int fi = idx >> 6, lane = idx & 63;
    int ntile = fi / 3, kstep = fi - ntile * 3;
    int n = ntile * 16 + (lane & 15), k0 = kstep * 32 + (lane >> 4) * 8;
#pragma unroll
    for (int j = 0; j < 8; ++j)
      qwp[(size_t)idx * 8 + j] = f2bf(qw[(size_t)(k0 + j) * 576 + n]);
  } else if (idx < 6912 + 4608) {  // 72 frags * 64 lanes
    int i2 = idx - 6912;
    int fi = i2 >> 6, lane = i2 & 63;
    int ntile = fi / 6, kstep = fi - ntile * 6;
    int n = ntile * 16 + (lane & 15), k0 = kstep * 32 + (lane >> 4) * 8;
#pragma unroll
    for (int j = 0; j < 8; ++j)
      awp[(size_t)i2 * 8 + j] = f2bf(aw[(size_t)(k0 + j) * 192 + n]);
  }
}

// ---------------- Kernel 1: LayerNorm(x) over DIM=96 -> xn (bf16) ----------
__global__ __launch_bounds__(256) void k1_ln1(const float* __restrict__ x,
                                              const float* __restrict__ g,
                                              const float* __restrict__ bta,
                                              unsigned short* __restrict__ xn) {
  int wave = threadIdx.x >> 6, lane = threadIdx.x & 63;
  int token = blockIdx.x * 4 + wave;
  const float* xr = x + (size_t)token * 96;
  float v0 = xr[lane];
  float v1 = (lane < 32) ? xr[64 + lane] : 0.f;
  float s = v0 + v1;
#pragma unroll
  for (int o = 32; o; o >>= 1) s += __shfl_xor(s, o);
  float mean = s * (1.f / 96.f);
  float d0 = v0 - mean;
  float d1 = (lane < 32) ? (v1 - mean) : 0.f;
  float q = d0 * d0 + d1 * d1;
#pragma unroll
  for (int o = 32; o; o >>= 1) q += __shfl_xor(q, o);
  float rstd = rsqrtf(q * (1.f / 96.f) + EPSV);
  unsigned short* xo = xn + (size_t)token * 96;
  xo[lane] = f2bf(d0 * rstd * g[lane] + bta[lane]);
  if (lane < 32) xo[64 + lane] = f2bf(d1 * rstd * g[64 + lane] + bta[64 + lane]);
}

// ------- Kernel 2: shortcut = maxpool2x2(xn @ proj_w + proj_b) -> d_out ---
__global__ __launch_bounds__(192) void k2_proj_pool(
    const unsigned short* __restrict__ xn, const float* __restrict__ pw,
    const float* __restrict__ pb, float* __restrict__ out) {
  __shared__ float sx[2][16][96];
  int tid = threadIdx.x;
  int pixbase = blockIdx.x * 8;
  int b = pixbase >> 14;
  int rem = pixbase & 16383;
  int hp = rem >> 7;
  int wpb = rem & 127;
  int r0 = hp * 2, c0 = wpb * 2;
  for (int i = 0; i < 16; ++i) {
    int idx = i * 192 + tid;
    int rr = idx / 1536;
    int r2 = idx - rr * 1536;
    const unsigned short* gp =
        xn + ((size_t)((b * 256 + r0 + rr) * 256 + c0)) * 96;
    ((float*)sx[rr])[r2] = bf2f(gp[r2]);
  }
  __syncthreads();
  int c = tid;
  float acc[8][4];
#pragma unroll
  for (int p = 0; p < 8; ++p)
#pragma unroll
    for (int s2 = 0; s2 < 4; ++s2) acc[p][s2] = 0.f;
  for (int k = 0; k < 96; ++k) {
    float w = pw[k * 192 + c];
#pragma unroll
    for (int p = 0; p < 8; ++p) {
#pragma unroll
      for (int s2 = 0; s2 < 4; ++s2) {
        acc[p][s2] += sx[s2 >> 1][p * 2 + (s2 & 1)][k] * w;
      }
    }
  }
  float bb = pb[c];
#pragma unroll
  for (int p = 0; p < 8; ++p) {
    float m = fmaxf(fmaxf(acc[p][0], acc[p][1]), fmaxf(acc[p][2], acc[p][3]));
    out[(size_t)(pixbase + p) * 192 + c] = m + bb;
  }
}

// --- Kernel 3: windowed attention via MFMA; d_out += attn_proj output ---
// One block (4 waves) per window. qkv GEMM 64x576 per window in bf16 MFMA.
__global__ __launch_bounds__(256) void k3_attn(
    const unsigned short* __restrict__ xnb, const unsigned short* __restrict__ qwp,
    const float* __restrict__ qb, const unsigned short* __restrict__ awp,
    const float* __restrict__ ab, float* __restrict__ out) {
  __shared__ unsigned short afrag[12][64][8];  // A frags: [mtile*3+kstep][lane][j]
  __shared__ unsigned short qT[64][72];        // q^T [d][token]
  __shared__ unsigned short kT[64][68];        // k^T [d][token]
  __shared__ unsigned short vT[64][72];        // v^T [d][token]
  __shared__ unsigned short qp[16][72];        // pooled q [p][d]
  __shared__ float sc[16][72];                 // scores
  __shared__ unsigned short pbuf[16][72];      // probs bf16 [p][key]
  __shared__ float ob[16][200];                // attn out [p][c], padded

  int tid = threadIdx.x, wave = tid >> 6, lane = tid & 63;
  int wi = blockIdx.x;
  int b = wi >> 10, nh = (wi >> 5) & 31, nw = wi & 31;
  int grow0 = nh * 8, gcol0 = nw * 8;
  int l15 = lane & 15, quad = lane >> 4;

  // ---- stage A fragments (xw 64x96 bf16), 12 frag-sets, 3 per wave ----
#pragma unroll
  for (int i = 0; i < 3; ++i) {
    int p = wave + 4 * i;  // = mtile*3 + kstep
    int mtile = p / 3, kstep = p - mtile * 3;
    int m = mtile * 16 + l15;
    int r = m >> 3, c = m & 7;
    const unsigned short* src =
        xnb + ((size_t)((b * 256 + grow0 + r) * 256 + gcol0 + c)) * 96 +
        kstep * 32 + quad * 8;
    *(uint4*)(&afrag[p][lane][0]) = *(const uint4*)src;
  }
  __syncthreads();

  // ---- load all A frags to registers (shared across heads) ----
  bf16x8 areg[4][3];
#pragma unroll
  for (int mt = 0; mt < 4; ++mt)
#pragma unroll
    for (int ks = 0; ks < 3; ++ks)
      areg[mt][ks] = *(const bf16x8*)(&afrag[mt * 3 + ks][lane][0]);

  for (int h = 0; h < 3; ++h) {
    // ---- qkv GEMM: wave handles local ntiles wave*3..wave*3+2 ----
#pragma unroll
    for (int nl = 0; nl < 3; ++nl) {
      int ln = wave * 3 + nl;  // 0..11
      int type = ln >> 2;      // 0=q,1=k,2=v
      int nt = ln & 3;
      int gnt = type * 12 + h * 4 + nt;  // ntile in qwp
      const unsigned short* bp = qwp + (size_t)gnt * 1536 + lane * 8;
      bf16x8 b0 = *(const bf16x8*)(bp);
      bf16x8 b1 = *(const bf16x8*)(bp + 512);
      bf16x8 b2 = *(const bf16x8*)(bp + 1024);
      int d = nt * 16 + l15;
      float bias = qb[type * 192 + h * 64 + d];
#pragma unroll
      for (int mt = 0; mt < 4; ++mt) {
        f32x4 acc = {0.f, 0.f, 0.f, 0.f};
        acc = __builtin_amdgcn_mfma_f32_16x16x32_bf16(areg[mt][0], b0, acc, 0, 0, 0);
        acc = __builtin_amdgcn_mfma_f32_16x16x32_bf16(areg[mt][1], b1, acc, 0, 0, 0);
        acc = __builtin_amdgcn_mfma_f32_16x16x32_bf16(areg[mt][2], b2, acc, 0, 0, 0);
        int t0 = mt * 16 + quad * 4;
        u16x4 pk;
#pragma unroll
        for (int r = 0; r < 4; ++r) pk[r] = f2bf(acc[r] + bias);
        if (type == 0)      *(u16x4*)(&qT[d][t0]) = pk;
        else if (type == 1) *(u16x4*)(&kT[d][t0]) = pk;
        else                *(u16x4*)(&vT[d][t0]) = pk;
      }
    }
    __syncthreads();

    // ---- pooled Q: max over 2x2 token groups ----
#pragma unroll
    for (int i = 0; i < 4; ++i) {
      int idx = i * 256 + tid;
      int p = idx >> 6, d = idx & 63;
      int t00 = (p >> 2) * 16 + (p & 3) * 2;
      float m0 = bf2f(qT[d][t00]), m1 = bf2f(qT[d][t00 + 1]);
      float m2 = bf2f(qT[d][t00 + 8]), m3 = bf2f(qT[d][t00 + 9]);
      qp[p][d] = f2bf(fmaxf(fmaxf(m0, m1), fmaxf(m2, m3)));
    }
    __syncthreads();

    // ---- S = 0.125 * Qp K^T : each wave one 16x16 N-tile (keys) ----
    {
      bf16x8 aq0 = *(const bf16x8*)(&qp[l15][quad * 8]);
      bf16x8 aq1 = *(const bf16x8*)(&qp[l15][32 + quad * 8]);
      int n = wave * 16 + l15;
      bf16x8 bk0, bk1;
#pragma unroll
      for (int j = 0; j < 8; ++j) {
        bk0[j] = (short)kT[quad * 8 + j][n];
        bk1[j] = (short)kT[32 + quad * 8 + j][n];
      }
      f32x4 s4 = {0.f, 0.f, 0.f, 0.f};
      s4 = __builtin_amdgcn_mfma_f32_16x16x32_bf16(aq0, bk0, s4, 0, 0, 0);
      s4 = __builtin_amdgcn_mfma_f32_16x16x32_bf16(aq1, bk1, s4, 0, 0, 0);
#pragma unroll
      for (int r = 0; r < 4; ++r) sc[quad * 4 + r][n] = s4[r] * 0.125f;
    }
    __syncthreads();

    // ---- softmax over 64 keys; 16 lanes per row ----
    {
      int row = tid >> 4, sub = tid & 15;
      float v0 = sc[row][sub], v1 = sc[row][sub + 16];
      float v2 = sc[row][sub + 32], v3 = sc[row][sub + 48];
      float mx = fmaxf(fmaxf(v0, v1), fmaxf(v2, v3));
#pragma unroll
      for (int o = 8; o; o >>= 1) mx = fmaxf(mx, __shfl_xor(mx, o));
      float e0 = __expf(v0 - mx), e1 = __expf(v1 - mx);
      float e2 = __expf(v2 - mx), e3 = __expf(v3 - mx);
      float sm = e0 + e1 + e2 + e3;
#pragma unroll
      for (int o = 8; o; o >>= 1) sm += __shfl_xor(sm, o);
      float inv = 1.f / sm;
      pbuf[row][sub] = f2bf(e0 * inv);
      pbuf[row][sub + 16] = f2bf(e1 * inv);
      pbuf[row][sub + 32] = f2bf(e2 * inv);
      pbuf[row][sub + 48] = f2bf(e3 * inv);
    }
    __syncthreads();

    // ---- O_h = P V : each wave one 16x16 N-tile (dims) ----
    {
      bf16x8 ap0 = *(const bf16x8*)(&pbuf[l15][quad * 8]);
      bf16x8 ap1 = *(const bf16x8*)(&pbuf[l15][32 + quad * 8]);
      int d = wave * 16 + l15;
      bf16x8 bv0 = *(const bf16x8*)(&vT[d][quad * 8]);
      bf16x8 bv1 = *(const bf16x8*)(&vT[d][32 + quad * 8]);
      f32x4 o4 = {0.f, 0.f, 0.f, 0.f};
      o4 = __builtin_amdgcn_mfma_f32_16x16x32_bf16(ap0, bv0, o4, 0, 0, 0);
      o4 = __builtin_amdgcn_mfma_f32_16x16x32_bf16(ap1, bv1, o4, 0, 0, 0);
#pragma unroll
      for (int r = 0; r < 4; ++r) ob[quad * 4 + r][h * 64 + d] = o4[r];
    }
    __syncthreads();  // also protects qT/kT/vT for next head
  }

  // ---- attn_proj: O(16x192) @ aw(192x192) + ab, += into out ----
  bf16x8 ao[6];
#pragma unroll
  for (int ks = 0; ks < 6; ++ks) {
    f32x4 lo = *(const f32x4*)(&ob[l15][ks * 32 + quad * 8]);
    f32x4 hi = *(const f32x4*)(&ob[l15][ks * 32 + quad * 8 + 4]);
#pragma unroll
    for (int j = 0; j < 4; ++j) {
      ao[ks][j] = (short)f2bf(lo[j]);
      ao[ks][4 + j] = (short)f2bf(hi[j]);
    }
  }
#pragma unroll
  for (int nl = 0; nl < 3; ++nl) {
    int ntl = wave * 3 + nl;
    const unsigned short* bp = awp + (size_t)ntl * 3072 + lane * 8;
    f32x4 acc = {0.f, 0.f, 0.f, 0.f};
#pragma unroll
    for (int ks = 0; ks < 6; ++ks) {
      bf16x8 bw = *(const bf16x8*)(bp + ks * 512);
      acc = __builtin_amdgcn_mfma_f32_16x16x32_bf16(ao[ks], bw, acc, 0, 0, 0);
    }
    int cc = ntl * 16 + l15;
    float bias = ab[cc];
#pragma unroll
    for (int r = 0; r < 4; ++r) {
      int p = quad * 4 + r;
      int hp = nh * 4 + (p >> 2), wp2 = nw * 4 + (p & 3);
      size_t oi = ((size_t)((b * 128 + hp) * 128 + wp2)) * 192 + cc;
      out[oi] += acc[r] + bias;
    }
  }
}

// ------- Kernel 4: LN2 + MLP (GELU exact) + residual; in-place on d_out ---
__global__ __launch_bounds__(256) void k4_mlp(float* __restrict__ y,
                                              const float* __restrict__ g,
                                              const float* __restrict__ bt,
                                              const float* __restrict__ w1,
                                              const float* __restrict__ b1,
                                              const float* __restrict__ w2,
                                              const float* __restrict__ b2) {
  __shared__ float yn[16][192];
  __shared__ float hh[16][768];
  int tid = threadIdx.x;
  int wave = tid >> 6, lane = tid & 63;
  size_t tokbase = (size_t)blockIdx.x * 16;
  for (int j = 0; j < 4; ++j) {
    int tt = wave * 4 + j;
    const float* yr = y + (tokbase + tt) * 192;
    float v0 = yr[lane], v1 = yr[64 + lane], v2 = yr[128 + lane];
    float s = v0 + v1 + v2;
#pragma unroll
    for (int o = 32; o; o >>= 1) s += __shfl_xor(s, o);
    float mean = s * (1.f / 192.f);
    float d0 = v0 - mean, d1 = v1 - mean, d2 = v2 - mean;
    float q = d0 * d0 + d1 * d1 + d2 * d2;
#pragma unroll
    for (int o = 32; o; o >>= 1) q += __shfl_xor(q, o);
    float rstd = rsqrtf(q * (1.f / 192.f) + EPSV);
    yn[tt][lane] = d0 * rstd * g[lane] + bt[lane];
    yn[tt][64 + lane] = d1 * rstd * g[64 + lane] + bt[64 + lane];
    yn[tt][128 + lane] = d2 * rstd * g[128 + lane] + bt[128 + lane];
  }
  __syncthreads();
  for (int cs = 0; cs < 3; ++cs) {
    int c = cs * 256 + tid;
    float acc[16];
    float bb = b1[c];
#pragma unroll
    for (int t = 0; t < 16; ++t) acc[t] = bb;
    for (int k = 0; k < 192; ++k) {
      float w = w1[k * 768 + c];
#pragma unroll
      for (int t = 0; t < 16; ++t) acc[t] += yn[t][k] * w;
    }
#pragma unroll
    for (int t = 0; t < 16; ++t) {
      float v = acc[t];
      hh[t][c] = 0.5f * v * (1.f + erff(v * 0.70710678118654752f));
    }
  }
  __syncthreads();
  if (tid < 192) {
    int c = tid;
    float acc[16];
    float bb = b2[c];
#pragma unroll
    for (int t = 0; t < 16; ++t) acc[t] = bb;
    for (int k = 0; k < 768; ++k) {
      float w = w2[k * 192 + c];
#pragma unroll
      for (int t = 0; t < 16; ++t) acc[t] += hh[t][k] * w;
    }
#pragma unroll
    for (int t = 0; t < 16; ++t) {
      size_t oi = (tokbase + t) * 192 + c;
      y[oi] += acc[t];
    }
  }
}

extern "C" void kernel_launch(void* const* d_in, const int* in_sizes, int n_in,
                              void* d_out, int out_size, void* d_ws,
                              size_t ws_size, hipStream_t stream) {
  const float* x = (const float*)d_in[0];
  const float* n1g = (const float*)d_in[1];
  const float* n1b = (const float*)d_in[2];
  const float* pw = (const float*)d_in[3];
  const float* pb = (const float*)d_in[4];
  const float* qw = (const float*)d_in[5];
  const float* qb = (const float*)d_in[6];
  const float* aw = (const float*)d_in[7];
  const float* ab = (const float*)d_in[8];
  const float* n2g = (const float*)d_in[9];
  const float* n2b = (const float*)d_in[10];
  const float* w1 = (const float*)d_in[11];
  const float* b1 = (const float*)d_in[12];
  const float* w2 = (const float*)d_in[13];
  const float* b2 = (const float*)d_in[14];
  float* out = (float*)d_out;

  // ws layout: xn bf16 [262144][96] = 50,331,648 B; qwp = 110,592 B; awp = 73,728 B
  unsigned short* xnb = (unsigned short*)d_ws;
  unsigned short* qwp = (unsigned short*)((char*)d_ws + 50331648);
  unsigned short* awp = (unsigned short*)((char*)d_ws + 50331648 + 110592);

  hipLaunchKernelGGL(k0_pack, dim3(45), dim3(256), 0, stream, qw, aw, qwp, awp);
  hipLaunchKernelGGL(k1_ln1, dim3(65536), dim3(256), 0, stream, x, n1g, n1b, xnb);
  hipLaunchKernelGGL(k2_proj_pool, dim3(8192), dim3(192), 0, stream, xnb, pw, pb, out);
  hipLaunchKernelGGL(k3_attn, dim3(4096), dim3(256), 0, stream, xnb, qwp, qb, awp, ab, out);
  hipLaunchKernelGGL(k4_mlp, dim3(4096), dim3(256), 0, stream, out, n2g, n2b, w1, b1, w2, b2);
}

// Round 3
// 439.952 us; speedup vs baseline: 10.7962x; 3.5842x over previous
//
#include <hip/hip_runtime.h>
#include <hip/hip_bf16.h>
#include <math.h>

#define EPSV 1e-6f

typedef __attribute__((ext_vector_type(8))) short bf16x8;
typedef __attribute__((ext_vector_type(4))) float f32x4;
typedef __attribute__((ext_vector_type(4))) unsigned short u16x4;

__device__ inline float bf2f(unsigned short u) {
  union { unsigned int i; float f; } v;
  v.i = ((unsigned int)u) << 16;
  return v.f;
}
__device__ inline unsigned short f2bf(float f) {
  __hip_bfloat16 h = __float2bfloat16(f);  // RNE
  return __builtin_bit_cast(unsigned short, h);
}

// ---- Kernel 0: pack all weights into MFMA B-fragment layout (bf16) ----
// B-frag: [ntile][kstep][lane][8], n=ntile*16+(lane&15), k=kstep*32+(lane>>4)*8+j
// qw 96x576: 36nt x 3ks | aw 192x192: 12 x 6 | w1 192x768: 48 x 6
// w2 768x192: 12 x 24   | pw 96x192: 12 x 3
__global__ __launch_bounds__(256) void k0_pack(
    const float* __restrict__ qw, const float* __restrict__ aw,
    const float* __restrict__ w1, const float* __restrict__ w2,
    const float* __restrict__ pw, unsigned short* __restrict__ qwp,
    unsigned short* __restrict__ awp, unsigned short* __restrict__ w1p,
    unsigned short* __restrict__ w2p, unsigned short* __restrict__ pwp) {
  int idx = blockIdx.x * 256 + threadIdx.x;
  int lane = idx & 63;
  int l15 = lane & 15, quad = lane >> 4;
  if (idx < 6912) {
    int fi = idx >> 6;
    int ntile = fi / 3, kstep = fi - ntile * 3;
    int n = ntile * 16 + l15, k0 = kstep * 32 + quad * 8;
#pragma unroll
    for (int j = 0; j < 8; ++j)
      qwp[(size_t)idx * 8 + j] = f2bf(qw[(size_t)(k0 + j) * 576 + n]);
  } else if (idx < 11520) {
    int i2 = idx - 6912;
    int fi = i2 >> 6;
    int ntile = fi / 6, kstep = fi - ntile * 6;
    int n = ntile * 16 + l15, k0 = kstep * 32 + quad * 8;
#pragma unroll
    for (int j = 0; j < 8; ++j)
      awp[(size_t)i2 * 8 + j] = f2bf(aw[(size_t)(k0 + j) * 192 + n]);
  } else if (idx < 29952) {
    int i3 = idx - 11520;
    int fi = i3 >> 6;
    int ntile = fi / 6, kstep = fi - ntile * 6;
    int n = ntile * 16 + l15, k0 = kstep * 32 + quad * 8;
#pragma unroll
    for (int j = 0; j < 8; ++j)
      w1p[(size_t)i3 * 8 + j] = f2bf(w1[(size_t)(k0 + j) * 768 + n]);
  } else if (idx < 48384) {
    int i4 = idx - 29952;
    int fi = i4 >> 6;
    int ntile = fi / 24, kstep = fi - ntile * 24;
    int n = ntile * 16 + l15, k0 = kstep * 32 + quad * 8;
#pragma unroll
    for (int j = 0; j < 8; ++j)
      w2p[(size_t)i4 * 8 + j] = f2bf(w2[(size_t)(k0 + j) * 192 + n]);
  } else if (idx < 50688) {
    int i5 = idx - 48384;
    int fi = i5 >> 6;
    int ntile = fi / 3, kstep = fi - ntile * 3;
    int n = ntile * 16 + l15, k0 = kstep * 32 + quad * 8;
#pragma unroll
    for (int j = 0; j < 8; ++j)
      pwp[(size_t)i5 * 8 + j] = f2bf(pw[(size_t)(k0 + j) * 192 + n]);
  }
}

// ---------------- Kernel 1: LayerNorm(x) over DIM=96 -> xn (bf16) ----------
__global__ __launch_bounds__(256) void k1_ln1(const float* __restrict__ x,
                                              const float* __restrict__ g,
                                              const float* __restrict__ bta,
                                              unsigned short* __restrict__ xn) {
  int wave = threadIdx.x >> 6, lane = threadIdx.x & 63;
  int token = blockIdx.x * 4 + wave;
  const float* xr = x + (size_t)token * 96;
  float v0 = xr[lane];
  float v1 = (lane < 32) ? xr[64 + lane] : 0.f;
  float s = v0 + v1;
#pragma unroll
  for (int o = 32; o; o >>= 1) s += __shfl_xor(s, o);
  float mean = s * (1.f / 96.f);
  float d0 = v0 - mean;
  float d1 = (lane < 32) ? (v1 - mean) : 0.f;
  float q = d0 * d0 + d1 * d1;
#pragma unroll
  for (int o = 32; o; o >>= 1) q += __shfl_xor(q, o);
  float rstd = rsqrtf(q * (1.f / 96.f) + EPSV);
  unsigned short* xo = xn + (size_t)token * 96;
  xo[lane] = f2bf(d0 * rstd * g[lane] + bta[lane]);
  if (lane < 32) xo[64 + lane] = f2bf(d1 * rstd * g[64 + lane] + bta[64 + lane]);
}

// -- Kernel 2: shortcut = maxpool2x2(xn @ proj_w + proj_b) via MFMA -> d_out --
// Block: 2 token rows x 16 cols (2 mtiles), 8 pooled pixels. No LDS.
// Pooling: token m = row*16+col -> mtile=row; within a lane, acc rows r pair
// adjacent cols, so pool = max over {mt0,mt1} x {r,r+1} all lane-local.
__global__ __launch_bounds__(256) void k2_proj_pool(
    const unsigned short* __restrict__ xnb, const unsigned short* __restrict__ pwp,
    const float* __restrict__ pb, float* __restrict__ out) {
  int tid = threadIdx.x, wave = tid >> 6, lane = tid & 63;
  int l15 = lane & 15, quad = lane >> 4;
  int pixbase = blockIdx.x * 8;
  int b = pixbase >> 14;
  int rem = pixbase & 16383;
  int hp = rem >> 7;
  int wp0 = rem & 127;
  int r0 = hp * 2, c0 = wp0 * 2;
  // A-frags direct from global: token (b, r0+mt, c0+l15)
  bf16x8 a[2][3];
#pragma unroll
  for (int mt = 0; mt < 2; ++mt) {
    const unsigned short* src =
        xnb + ((size_t)((b * 256 + r0 + mt) * 256 + c0 + l15)) * 96 + quad * 8;
#pragma unroll
    for (int ks = 0; ks < 3; ++ks)
      a[mt][ks] = *(const bf16x8*)(src + ks * 32);
  }
#pragma unroll
  for (int nl = 0; nl < 3; ++nl) {
    int nt = wave * 3 + nl;
    const unsigned short* bp = pwp + ((size_t)(nt * 3) * 64 + lane) * 8;
    f32x4 t0 = {0.f, 0.f, 0.f, 0.f}, t1 = {0.f, 0.f, 0.f, 0.f};
#pragma unroll
    for (int ks = 0; ks < 3; ++ks) {
      bf16x8 bw = *(const bf16x8*)(bp + ks * 512);
      t0 = __builtin_amdgcn_mfma_f32_16x16x32_bf16(a[0][ks], bw, t0, 0, 0, 0);
      t1 = __builtin_amdgcn_mfma_f32_16x16x32_bf16(a[1][ks], bw, t1, 0, 0, 0);
    }
    int c = nt * 16 + l15;
    float bb = pb[c];
    float m0 = fmaxf(fmaxf(t0[0], t0[1]), fmaxf(t1[0], t1[1]));
    float m1 = fmaxf(fmaxf(t0[2], t0[3]), fmaxf(t1[2], t1[3]));
    out[(size_t)(pixbase + quad * 2 + 0) * 192 + c] = m0 + bb;
    out[(size_t)(pixbase + quad * 2 + 1) * 192 + c] = m1 + bb;
  }
}

// --- Kernel 3: windowed attention via MFMA; d_out += attn_proj output ---
__global__ __launch_bounds__(256) void k3_attn(
    const unsigned short* __restrict__ xnb, const unsigned short* __restrict__ qwp,
    const float* __restrict__ qb, const unsigned short* __restrict__ awp,
    const float* __restrict__ ab, float* __restrict__ out) {
  __shared__ unsigned short afrag[12][64][8];
  __shared__ unsigned short qT[64][72];
  __shared__ unsigned short kT[64][68];
  __shared__ unsigned short vT[64][72];
  __shared__ unsigned short qp[16][72];
  __shared__ float sc[16][72];
  __shared__ unsigned short pbuf[16][72];
  __shared__ float ob[16][200];

  int tid = threadIdx.x, wave = tid >> 6, lane = tid & 63;
  int wi = blockIdx.x;
  int b = wi >> 10, nh = (wi >> 5) & 31, nw = wi & 31;
  int grow0 = nh * 8, gcol0 = nw * 8;
  int l15 = lane & 15, quad = lane >> 4;

#pragma unroll
  for (int i = 0; i < 3; ++i) {
    int p = wave + 4 * i;
    int mtile = p / 3, kstep = p - mtile * 3;
    int m = mtile * 16 + l15;
    int r = m >> 3, c = m & 7;
    const unsigned short* src =
        xnb + ((size_t)((b * 256 + grow0 + r) * 256 + gcol0 + c)) * 96 +
        kstep * 32 + quad * 8;
    *(uint4*)(&afrag[p][lane][0]) = *(const uint4*)src;
  }
  __syncthreads();

  bf16x8 areg[4][3];
#pragma unroll
  for (int mt = 0; mt < 4; ++mt)
#pragma unroll
    for (int ks = 0; ks < 3; ++ks)
      areg[mt][ks] = *(const bf16x8*)(&afrag[mt * 3 + ks][lane][0]);

  for (int h = 0; h < 3; ++h) {
#pragma unroll
    for (int nl = 0; nl < 3; ++nl) {
      int ln = wave * 3 + nl;
      int type = ln >> 2;
      int nt = ln & 3;
      int gnt = type * 12 + h * 4 + nt;
      const unsigned short* bp = qwp + (size_t)gnt * 1536 + lane * 8;
      bf16x8 b0 = *(const bf16x8*)(bp);
      bf16x8 b1 = *(const bf16x8*)(bp + 512);
      bf16x8 b2 = *(const bf16x8*)(bp + 1024);
      int d = nt * 16 + l15;
      float bias = qb[type * 192 + h * 64 + d];
#pragma unroll
      for (int mt = 0; mt < 4; ++mt) {
        f32x4 acc = {0.f, 0.f, 0.f, 0.f};
        acc = __builtin_amdgcn_mfma_f32_16x16x32_bf16(areg[mt][0], b0, acc, 0, 0, 0);
        acc = __builtin_amdgcn_mfma_f32_16x16x32_bf16(areg[mt][1], b1, acc, 0, 0, 0);
        acc = __builtin_amdgcn_mfma_f32_16x16x32_bf16(areg[mt][2], b2, acc, 0, 0, 0);
        int t0 = mt * 16 + quad * 4;
        u16x4 pk;
#pragma unroll
        for (int r = 0; r < 4; ++r) pk[r] = f2bf(acc[r] + bias);
        if (type == 0)      *(u16x4*)(&qT[d][t0]) = pk;
        else if (type == 1) *(u16x4*)(&kT[d][t0]) = pk;
        else                *(u16x4*)(&vT[d][t0]) = pk;
      }
    }
    __syncthreads();

#pragma unroll
    for (int i = 0; i < 4; ++i) {
      int idx = i * 256 + tid;
      int p = idx >> 6, d = idx & 63;
      int t00 = (p >> 2) * 16 + (p & 3) * 2;
      float m0 = bf2f(qT[d][t00]), m1 = bf2f(qT[d][t00 + 1]);
      float m2 = bf2f(qT[d][t00 + 8]), m3 = bf2f(qT[d][t00 + 9]);
      qp[p][d] = f2bf(fmaxf(fmaxf(m0, m1), fmaxf(m2, m3)));
    }
    __syncthreads();

    {
      bf16x8 aq0 = *(const bf16x8*)(&qp[l15][quad * 8]);
      bf16x8 aq1 = *(const bf16x8*)(&qp[l15][32 + quad * 8]);
      int n = wave * 16 + l15;
      bf16x8 bk0, bk1;
#pragma unroll
      for (int j = 0; j < 8; ++j) {
        bk0[j] = (short)kT[quad * 8 + j][n];
        bk1[j] = (short)kT[32 + quad * 8 + j][n];
      }
      f32x4 s4 = {0.f, 0.f, 0.f, 0.f};
      s4 = __builtin_amdgcn_mfma_f32_16x16x32_bf16(aq0, bk0, s4, 0, 0, 0);
      s4 = __builtin_amdgcn_mfma_f32_16x16x32_bf16(aq1, bk1, s4, 0, 0, 0);
#pragma unroll
      for (int r = 0; r < 4; ++r) sc[quad * 4 + r][n] = s4[r] * 0.125f;
    }
    __syncthreads();

    {
      int row = tid >> 4, sub = tid & 15;
      float v0 = sc[row][sub], v1 = sc[row][sub + 16];
      float v2 = sc[row][sub + 32], v3 = sc[row][sub + 48];
      float mx = fmaxf(fmaxf(v0, v1), fmaxf(v2, v3));
#pragma unroll
      for (int o = 8; o; o >>= 1) mx = fmaxf(mx, __shfl_xor(mx, o));
      float e0 = __expf(v0 - mx), e1 = __expf(v1 - mx);
      float e2 = __expf(v2 - mx), e3 = __expf(v3 - mx);
      float sm = e0 + e1 + e2 + e3;
#pragma unroll
      for (int o = 8; o; o >>= 1) sm += __shfl_xor(sm, o);
      float inv = 1.f / sm;
      pbuf[row][sub] = f2bf(e0 * inv);
      pbuf[row][sub + 16] = f2bf(e1 * inv);
      pbuf[row][sub + 32] = f2bf(e2 * inv);
      pbuf[row][sub + 48] = f2bf(e3 * inv);
    }
    __syncthreads();

    {
      bf16x8 ap0 = *(const bf16x8*)(&pbuf[l15][quad * 8]);
      bf16x8 ap1 = *(const bf16x8*)(&pbuf[l15][32 + quad * 8]);
      int d = wave * 16 + l15;
      bf16x8 bv0 = *(const bf16x8*)(&vT[d][quad * 8]);
      bf16x8 bv1 = *(const bf16x8*)(&vT[d][32 + quad * 8]);
      f32x4 o4 = {0.f, 0.f, 0.f, 0.f};
      o4 = __builtin_amdgcn_mfma_f32_16x16x32_bf16(ap0, bv0, o4, 0, 0, 0);
      o4 = __builtin_amdgcn_mfma_f32_16x16x32_bf16(ap1, bv1, o4, 0, 0, 0);
#pragma unroll
      for (int r = 0; r < 4; ++r) ob[quad * 4 + r][h * 64 + d] = o4[r];
    }
    __syncthreads();
  }

  bf16x8 ao[6];
#pragma unroll
  for (int ks = 0; ks < 6; ++ks) {
    f32x4 lo = *(const f32x4*)(&ob[l15][ks * 32 + quad * 8]);
    f32x4 hi = *(const f32x4*)(&ob[l15][ks * 32 + quad * 8 + 4]);
#pragma unroll
    for (int j = 0; j < 4; ++j) {
      ao[ks][j] = (short)f2bf(lo[j]);
      ao[ks][4 + j] = (short)f2bf(hi[j]);
    }
  }
#pragma unroll
  for (int nl = 0; nl < 3; ++nl) {
    int ntl = wave * 3 + nl;
    const unsigned short* bp = awp + (size_t)ntl * 3072 + lane * 8;
    f32x4 acc = {0.f, 0.f, 0.f, 0.f};
#pragma unroll
    for (int ks = 0; ks < 6; ++ks) {
      bf16x8 bw = *(const bf16x8*)(bp + ks * 512);
      acc = __builtin_amdgcn_mfma_f32_16x16x32_bf16(ao[ks], bw, acc, 0, 0, 0);
    }
    int cc = ntl * 16 + l15;
    float bias = ab[cc];
#pragma unroll
    for (int r = 0; r < 4; ++r) {
      int p = quad * 4 + r;
      int hp = nh * 4 + (p >> 2), wp2 = nw * 4 + (p & 3);
      size_t oi = ((size_t)((b * 128 + hp) * 128 + wp2)) * 192 + cc;
      out[oi] += acc[r] + bias;
    }
  }
}

// ------- Kernel 4: LN2 + MLP via MFMA + residual; in-place on d_out -------
// 32 tokens/block (2 mtiles). GEMM1 in 4 hidden-chunks of 192; GELU; GEMM2
// accumulated across chunks in registers. LDS 25 KB.
__global__ __launch_bounds__(256) void k4_mlp(
    float* __restrict__ y, const float* __restrict__ g,
    const float* __restrict__ bt, const unsigned short* __restrict__ w1p,
    const float* __restrict__ b1, const unsigned short* __restrict__ w2p,
    const float* __restrict__ b2) {
  __shared__ unsigned short yn[32][196];
  __shared__ unsigned short hls[32][196];
  int tid = threadIdx.x, wave = tid >> 6, lane = tid & 63;
  int l15 = lane & 15, quad = lane >> 4;
  size_t tokbase = (size_t)blockIdx.x * 32;

  // LN2: 8 tokens per wave, bf16 into LDS
  for (int j = 0; j < 8; ++j) {
    int tt = wave * 8 + j;
    const float* yr = y + (tokbase + tt) * 192;
    float v0 = yr[lane], v1 = yr[64 + lane], v2 = yr[128 + lane];
    float s = v0 + v1 + v2;
#pragma unroll
    for (int o = 32; o; o >>= 1) s += __shfl_xor(s, o);
    float mean = s * (1.f / 192.f);
    float d0 = v0 - mean, d1 = v1 - mean, d2 = v2 - mean;
    float q = d0 * d0 + d1 * d1 + d2 * d2;
#pragma unroll
    for (int o = 32; o; o >>= 1) q += __shfl_xor(q, o);
    float rstd = rsqrtf(q * (1.f / 192.f) + EPSV);
    yn[tt][lane] = f2bf(d0 * rstd * g[lane] + bt[lane]);
    yn[tt][64 + lane] = f2bf(d1 * rstd * g[64 + lane] + bt[64 + lane]);
    yn[tt][128 + lane] = f2bf(d2 * rstd * g[128 + lane] + bt[128 + lane]);
  }
  __syncthreads();

  f32x4 acc2[3][2];
#pragma unroll
  for (int nl = 0; nl < 3; ++nl)
#pragma unroll
    for (int mt = 0; mt < 2; ++mt) acc2[nl][mt] = (f32x4){0.f, 0.f, 0.f, 0.f};

  for (int c = 0; c < 4; ++c) {
    // A-frags for GEMM1 from yn
    bf16x8 ar[2][6];
#pragma unroll
    for (int mt = 0; mt < 2; ++mt)
#pragma unroll
      for (int ks = 0; ks < 6; ++ks)
        ar[mt][ks] = *(const bf16x8*)(&yn[mt * 16 + l15][ks * 32 + quad * 8]);
    // GEMM1: 192 hidden cols this chunk; wave covers 3 ntiles
#pragma unroll
    for (int nl = 0; nl < 3; ++nl) {
      int gnt = c * 12 + wave * 3 + nl;
      const unsigned short* bp = w1p + ((size_t)(gnt * 6) * 64 + lane) * 8;
      f32x4 t0 = {0.f, 0.f, 0.f, 0.f}, t1 = {0.f, 0.f, 0.f, 0.f};
#pragma unroll
      for (int ks = 0; ks < 6; ++ks) {
        bf16x8 bw = *(const bf16x8*)(bp + ks * 512);
        t0 = __builtin_amdgcn_mfma_f32_16x16x32_bf16(ar[0][ks], bw, t0, 0, 0, 0);
        t1 = __builtin_amdgcn_mfma_f32_16x16x32_bf16(ar[1][ks], bw, t1, 0, 0, 0);
      }
      int lcol = wave * 48 + nl * 16 + l15;
      float bias = b1[c * 192 + lcol];
#pragma unroll
      for (int r = 0; r < 4; ++r) {
        float v = t0[r] + bias;
        hls[quad * 4 + r][lcol] =
            f2bf(0.5f * v * (1.f + erff(v * 0.70710678118654752f)));
        float w = t1[r] + bias;
        hls[16 + quad * 4 + r][lcol] =
            f2bf(0.5f * w * (1.f + erff(w * 0.70710678118654752f)));
      }
    }
    __syncthreads();
    // GEMM2 accumulate: K-chunk of 192 (6 ksteps)
    bf16x8 hr[2][6];
#pragma unroll
    for (int mt = 0; mt < 2; ++mt)
#pragma unroll
      for (int ks = 0; ks < 6; ++ks)
        hr[mt][ks] = *(const bf16x8*)(&hls[mt * 16 + l15][ks * 32 + quad * 8]);
#pragma unroll
    for (int nl = 0; nl < 3; ++nl) {
      int nt2 = wave * 3 + nl;
      const unsigned short* bp =
          w2p + ((size_t)((nt2 * 24 + c * 6)) * 64 + lane) * 8;
#pragma unroll
      for (int ks = 0; ks < 6; ++ks) {
        bf16x8 bw = *(const bf16x8*)(bp + ks * 512);
        acc2[nl][0] =
            __builtin_amdgcn_mfma_f32_16x16x32_bf16(hr[0][ks], bw, acc2[nl][0], 0, 0, 0);
        acc2[nl][1] =
            __builtin_amdgcn_mfma_f32_16x16x32_bf16(hr[1][ks], bw, acc2[nl][1], 0, 0, 0);
      }
    }
    __syncthreads();
  }

  // epilogue: bias + residual, in place
#pragma unroll
  for (int nl = 0; nl < 3; ++nl) {
    int col = (wave * 3 + nl) * 16 + l15;
    float bias = b2[col];
#pragma unroll
    for (int mt = 0; mt < 2; ++mt) {
#pragma unroll
      for (int r = 0; r < 4; ++r) {
        size_t oi = (tokbase + mt * 16 + quad * 4 + r) * 192 + col;
        y[oi] += acc2[nl][mt][r] + bias;
      }
    }
  }
}

extern "C" void kernel_launch(void* const* d_in, const int* in_sizes, int n_in,
                              void* d_out, int out_size, void* d_ws,
                              size_t ws_size, hipStream_t stream) {
  const float* x = (const float*)d_in[0];
  const float* n1g = (const float*)d_in[1];
  const float* n1b = (const float*)d_in[2];
  const float* pw = (const float*)d_in[3];
  const float* pb = (const float*)d_in[4];
  const float* qw = (const float*)d_in[5];
  const float* qb = (const float*)d_in[6];
  const float* aw = (const float*)d_in[7];
  const float* ab = (const float*)d_in[8];
  const float* n2g = (const float*)d_in[9];
  const float* n2b = (const float*)d_in[10];
  const float* w1 = (const float*)d_in[11];
  const float* b1 = (const float*)d_in[12];
  const float* w2 = (const float*)d_in[13];
  const float* b2 = (const float*)d_in[14];
  float* out = (float*)d_out;

  // ws layout (bytes):
  char* wsb = (char*)d_ws;
  unsigned short* xnb = (unsigned short*)wsb;                   // 50,331,648
  unsigned short* qwp = (unsigned short*)(wsb + 50331648);      //    110,592
  unsigned short* awp = (unsigned short*)(wsb + 50442240);      //     73,728
  unsigned short* w1p = (unsigned short*)(wsb + 50515968);      //    294,912
  unsigned short* w2p = (unsigned short*)(wsb + 50810880);      //    294,912
  unsigned short* pwp = (unsigned short*)(wsb + 51105792);      //     36,864

  hipLaunchKernelGGL(k0_pack, dim3(198), dim3(256), 0, stream, qw, aw, w1, w2,
                     pw, qwp, awp, w1p, w2p, pwp);
  hipLaunchKernelGGL(k1_ln1, dim3(65536), dim3(256), 0, stream, x, n1g, n1b, xnb);
  hipLaunchKernelGGL(k2_proj_pool, dim3(8192), dim3(256), 0, stream, xnb, pwp, pb, out);
  hipLaunchKernelGGL(k3_attn, dim3(4096), dim3(256), 0, stream, xnb, qwp, qb, awp, ab, out);
  hipLaunchKernelGGL(k4_mlp, dim3(2048), dim3(256), 0, stream, out, n2g, n2b, w1p, b1, w2p, b2);
}

// Round 4
// 427.023 us; speedup vs baseline: 11.1231x; 1.0303x over previous
//
#include <hip/hip_runtime.h>
#include <hip/hip_bf16.h>
#include <math.h>

#define EPSV 1e-6f

typedef __attribute__((ext_vector_type(8))) short bf16x8;
typedef __attribute__((ext_vector_type(4))) float f32x4;
typedef __attribute__((ext_vector_type(4))) unsigned short u16x4;

__device__ inline float bf2f(unsigned short u) {
  union { unsigned int i; float f; } v;
  v.i = ((unsigned int)u) << 16;
  return v.f;
}
__device__ inline unsigned short f2bf(float f) {
  __hip_bfloat16 h = __float2bfloat16(f);  // RNE
  return __builtin_bit_cast(unsigned short, h);
}
// tanh-GELU, NaN-safe: v - v/(1+exp(2c(v+0.044715 v^3)))
__device__ inline float fast_gelu(float v) {
  float u = 1.5957691216057308f * (v + 0.044715f * v * v * v);
  return v - v / (1.f + __expf(u));
}

// ---- Kernel 0: pack all weights into MFMA B-fragment layout (bf16) ----
// B-frag: [ntile][kstep][lane][8], n=ntile*16+(lane&15), k=kstep*32+(lane>>4)*8+j
__global__ __launch_bounds__(256) void k0_pack(
    const float* __restrict__ qw, const float* __restrict__ aw,
    const float* __restrict__ w1, const float* __restrict__ w2,
    const float* __restrict__ pw, unsigned short* __restrict__ qwp,
    unsigned short* __restrict__ awp, unsigned short* __restrict__ w1p,
    unsigned short* __restrict__ w2p, unsigned short* __restrict__ pwp) {
  int idx = blockIdx.x * 256 + threadIdx.x;
  int lane = idx & 63;
  int l15 = lane & 15, quad = lane >> 4;
  if (idx < 6912) {
    int fi = idx >> 6;
    int ntile = fi / 3, kstep = fi - ntile * 3;
    int n = ntile * 16 + l15, k0 = kstep * 32 + quad * 8;
#pragma unroll
    for (int j = 0; j < 8; ++j)
      qwp[(size_t)idx * 8 + j] = f2bf(qw[(size_t)(k0 + j) * 576 + n]);
  } else if (idx < 11520) {
    int i2 = idx - 6912;
    int fi = i2 >> 6;
    int ntile = fi / 6, kstep = fi - ntile * 6;
    int n = ntile * 16 + l15, k0 = kstep * 32 + quad * 8;
#pragma unroll
    for (int j = 0; j < 8; ++j)
      awp[(size_t)i2 * 8 + j] = f2bf(aw[(size_t)(k0 + j) * 192 + n]);
  } else if (idx < 29952) {
    int i3 = idx - 11520;
    int fi = i3 >> 6;
    int ntile = fi / 6, kstep = fi - ntile * 6;
    int n = ntile * 16 + l15, k0 = kstep * 32 + quad * 8;
#pragma unroll
    for (int j = 0; j < 8; ++j)
      w1p[(size_t)i3 * 8 + j] = f2bf(w1[(size_t)(k0 + j) * 768 + n]);
  } else if (idx < 48384) {
    int i4 = idx - 29952;
    int fi = i4 >> 6;
    int ntile = fi / 24, kstep = fi - ntile * 24;
    int n = ntile * 16 + l15, k0 = kstep * 32 + quad * 8;
#pragma unroll
    for (int j = 0; j < 8; ++j)
      w2p[(size_t)i4 * 8 + j] = f2bf(w2[(size_t)(k0 + j) * 192 + n]);
  } else if (idx < 50688) {
    int i5 = idx - 48384;
    int fi = i5 >> 6;
    int ntile = fi / 3, kstep = fi - ntile * 3;
    int n = ntile * 16 + l15, k0 = kstep * 32 + quad * 8;
#pragma unroll
    for (int j = 0; j < 8; ++j)
      pwp[(size_t)i5 * 8 + j] = f2bf(pw[(size_t)(k0 + j) * 192 + n]);
  }
}

// -- Kernel 12: fused LN1 (-> xnb bf16) + proj + maxpool (-> d_out) --------
// Block = 2 rows x 16 cols of tokens = 8 pooled pixels. LN results stay in
// LDS for the proj MFMA (A row m = column-token so pooling is lane-local).
__global__ __launch_bounds__(256) void k12_ln_proj(
    const float* __restrict__ x, const float* __restrict__ g,
    const float* __restrict__ bta, const unsigned short* __restrict__ pwp,
    const float* __restrict__ pb, unsigned short* __restrict__ xnb,
    float* __restrict__ out) {
  __shared__ unsigned short xs[2][16][104];  // pad 96->104: 2-way banks, 16B rows
  int tid = threadIdx.x, wave = tid >> 6, lane = tid & 63;
  int l15 = lane & 15, quad = lane >> 4;
  int pixbase = blockIdx.x * 8;
  int b = pixbase >> 14;
  int rem = pixbase & 16383;
  int hp = rem >> 7;
  int wp0 = rem & 127;
  int r0 = hp * 2, c0 = wp0 * 2;

#pragma unroll
  for (int j = 0; j < 8; ++j) {
    int tt = wave * 8 + j;
    int rr = tt >> 4, cc = tt & 15;
    size_t tok = (size_t)((b * 256 + r0 + rr) * 256 + c0 + cc);
    const float* xr = x + tok * 96;
    float v0 = xr[lane];
    float v1 = (lane < 32) ? xr[64 + lane] : 0.f;
    float s = v0 + v1;
#pragma unroll
    for (int o = 32; o; o >>= 1) s += __shfl_xor(s, o);
    float mean = s * (1.f / 96.f);
    float d0 = v0 - mean;
    float d1 = (lane < 32) ? (v1 - mean) : 0.f;
    float q = d0 * d0 + d1 * d1;
#pragma unroll
    for (int o = 32; o; o >>= 1) q += __shfl_xor(q, o);
    float rstd = rsqrtf(q * (1.f / 96.f) + EPSV);
    unsigned short* xo = xnb + tok * 96;
    unsigned short e0 = f2bf(d0 * rstd * g[lane] + bta[lane]);
    xo[lane] = e0;
    xs[rr][cc][lane] = e0;
    if (lane < 32) {
      unsigned short e1 = f2bf(d1 * rstd * g[64 + lane] + bta[64 + lane]);
      xo[64 + lane] = e1;
      xs[rr][cc][64 + lane] = e1;
    }
  }
  __syncthreads();

  bf16x8 a[2][3];
#pragma unroll
  for (int mt = 0; mt < 2; ++mt)
#pragma unroll
    for (int ks = 0; ks < 3; ++ks)
      a[mt][ks] = *(const bf16x8*)(&xs[mt][l15][ks * 32 + quad * 8]);

#pragma unroll
  for (int nl = 0; nl < 3; ++nl) {
    int nt = wave * 3 + nl;
    const unsigned short* bp = pwp + ((size_t)(nt * 3) * 64 + lane) * 8;
    f32x4 t0 = {0.f, 0.f, 0.f, 0.f}, t1 = {0.f, 0.f, 0.f, 0.f};
#pragma unroll
    for (int ks = 0; ks < 3; ++ks) {
      bf16x8 bw = *(const bf16x8*)(bp + ks * 512);
      t0 = __builtin_amdgcn_mfma_f32_16x16x32_bf16(a[0][ks], bw, t0, 0, 0, 0);
      t1 = __builtin_amdgcn_mfma_f32_16x16x32_bf16(a[1][ks], bw, t1, 0, 0, 0);
    }
    int c = nt * 16 + l15;
    float bb = pb[c];
    float m0 = fmaxf(fmaxf(t0[0], t0[1]), fmaxf(t1[0], t1[1]));
    float m1 = fmaxf(fmaxf(t0[2], t0[3]), fmaxf(t1[2], t1[3]));
    out[(size_t)(pixbase + quad * 2 + 0) * 192 + c] = m0 + bb;
    out[(size_t)(pixbase + quad * 2 + 1) * 192 + c] = m1 + bb;
  }
}

// --- Kernel 3: windowed attention via MFMA; d_out += attn_proj output ---
// v2: A-frags from global (no afrag LDS), K token-major (vector B-frags for
// S), Q pooled in registers via shfl, attn-out kept bf16 in A-frag layout.
__global__ __launch_bounds__(256) void k3_attn(
    const unsigned short* __restrict__ xnb, const unsigned short* __restrict__ qwp,
    const float* __restrict__ qb, const unsigned short* __restrict__ awp,
    const float* __restrict__ ab, float* __restrict__ out) {
  __shared__ unsigned short kk[64][72];    // K [token][d]
  __shared__ unsigned short vT[64][72];    // V^T [d][token]
  __shared__ unsigned short qp[16][72];    // pooled Q [p][d]
  __shared__ float sc[16][72];             // scores
  __shared__ unsigned short pbuf[16][72];  // probs bf16 [p][key]
  __shared__ unsigned short obb[16][200];  // attn out bf16 [p][c]

  int tid = threadIdx.x, wave = tid >> 6, lane = tid & 63;
  int wi = blockIdx.x;
  int b = wi >> 10, nh = (wi >> 5) & 31, nw = wi & 31;
  int grow0 = nh * 8, gcol0 = nw * 8;
  int l15 = lane & 15, quad = lane >> 4;

  // A-frags (xw 64x96) straight from global; all 12 per wave
  bf16x8 areg[4][3];
#pragma unroll
  for (int mt = 0; mt < 4; ++mt) {
    int m = mt * 16 + l15;
    int r = m >> 3, c = m & 7;
    const unsigned short* src =
        xnb + ((size_t)((b * 256 + grow0 + r) * 256 + gcol0 + c)) * 96 + quad * 8;
#pragma unroll
    for (int ks = 0; ks < 3; ++ks)
      areg[mt][ks] = *(const bf16x8*)(src + ks * 32);
  }

  for (int h = 0; h < 3; ++h) {
    // ---- qkv GEMM; wave covers 3 of 12 ntiles ----
#pragma unroll
    for (int nl = 0; nl < 3; ++nl) {
      int ln = wave * 3 + nl;
      int type = ln >> 2;  // 0=q,1=k,2=v
      int nt = ln & 3;
      int gnt = type * 12 + h * 4 + nt;
      const unsigned short* bp = qwp + (size_t)gnt * 1536 + lane * 8;
      bf16x8 b0 = *(const bf16x8*)(bp);
      bf16x8 b1 = *(const bf16x8*)(bp + 512);
      bf16x8 b2 = *(const bf16x8*)(bp + 1024);
      int d = nt * 16 + l15;
      float bias = qb[type * 192 + h * 64 + d];
#pragma unroll
      for (int mt = 0; mt < 4; ++mt) {
        f32x4 acc = {0.f, 0.f, 0.f, 0.f};
        acc = __builtin_amdgcn_mfma_f32_16x16x32_bf16(areg[mt][0], b0, acc, 0, 0, 0);
        acc = __builtin_amdgcn_mfma_f32_16x16x32_bf16(areg[mt][1], b1, acc, 0, 0, 0);
        acc = __builtin_amdgcn_mfma_f32_16x16x32_bf16(areg[mt][2], b2, acc, 0, 0, 0);
        if (type == 0) {
          // 2x2 pool in-register: tokens (quad*4+r, +1) and (+8,+9) via quad^2
          float p0 = fmaxf(acc[0], acc[1]);
          float p1 = fmaxf(acc[2], acc[3]);
          float q0 = fmaxf(p0, __shfl_xor(p0, 32));
          float q1 = fmaxf(p1, __shfl_xor(p1, 32));
          if (quad < 2) {
            int p = mt * 4 + quad * 2;
            qp[p][d] = f2bf(q0 + bias);
            qp[p + 1][d] = f2bf(q1 + bias);
          }
        } else if (type == 1) {
          int t0 = mt * 16 + quad * 4;
#pragma unroll
          for (int r = 0; r < 4; ++r) kk[t0 + r][d] = f2bf(acc[r] + bias);
        } else {
          int t0 = mt * 16 + quad * 4;
          u16x4 pk;
#pragma unroll
          for (int r = 0; r < 4; ++r) pk[r] = f2bf(acc[r] + bias);
          *(u16x4*)(&vT[d][t0]) = pk;
        }
      }
    }
    __syncthreads();

    // ---- S = 0.125 * Qp K^T : each wave one 16-key tile ----
    {
      bf16x8 aq0 = *(const bf16x8*)(&qp[l15][quad * 8]);
      bf16x8 aq1 = *(const bf16x8*)(&qp[l15][32 + quad * 8]);
      int n = wave * 16 + l15;
      bf16x8 bk0 = *(const bf16x8*)(&kk[n][quad * 8]);
      bf16x8 bk1 = *(const bf16x8*)(&kk[n][32 + quad * 8]);
      f32x4 s4 = {0.f, 0.f, 0.f, 0.f};
      s4 = __builtin_amdgcn_mfma_f32_16x16x32_bf16(aq0, bk0, s4, 0, 0, 0);
      s4 = __builtin_amdgcn_mfma_f32_16x16x32_bf16(aq1, bk1, s4, 0, 0, 0);
#pragma unroll
      for (int r = 0; r < 4; ++r) sc[quad * 4 + r][n] = s4[r] * 0.125f;
    }
    __syncthreads();

    // ---- softmax over 64 keys; 16 lanes per row ----
    {
      int row = tid >> 4, sub = tid & 15;
      float v0 = sc[row][sub], v1 = sc[row][sub + 16];
      float v2 = sc[row][sub + 32], v3 = sc[row][sub + 48];
      float mx = fmaxf(fmaxf(v0, v1), fmaxf(v2, v3));
#pragma unroll
      for (int o = 8; o; o >>= 1) mx = fmaxf(mx, __shfl_xor(mx, o));
      float e0 = __expf(v0 - mx), e1 = __expf(v1 - mx);
      float e2 = __expf(v2 - mx), e3 = __expf(v3 - mx);
      float sm = e0 + e1 + e2 + e3;
#pragma unroll
      for (int o = 8; o; o >>= 1) sm += __shfl_xor(sm, o);
      float inv = 1.f / sm;
      pbuf[row][sub] = f2bf(e0 * inv);
      pbuf[row][sub + 16] = f2bf(e1 * inv);
      pbuf[row][sub + 32] = f2bf(e2 * inv);
      pbuf[row][sub + 48] = f2bf(e3 * inv);
    }
    __syncthreads();

    // ---- O_h = P V : each wave one 16-dim tile; write bf16 A-layout ----
    {
      bf16x8 ap0 = *(const bf16x8*)(&pbuf[l15][quad * 8]);
      bf16x8 ap1 = *(const bf16x8*)(&pbuf[l15][32 + quad * 8]);
      int d = wave * 16 + l15;
      bf16x8 bv0 = *(const bf16x8*)(&vT[d][quad * 8]);
      bf16x8 bv1 = *(const bf16x8*)(&vT[d][32 + quad * 8]);
      f32x4 o4 = {0.f, 0.f, 0.f, 0.f};
      o4 = __builtin_amdgcn_mfma_f32_16x16x32_bf16(ap0, bv0, o4, 0, 0, 0);
      o4 = __builtin_amdgcn_mfma_f32_16x16x32_bf16(ap1, bv1, o4, 0, 0, 0);
#pragma unroll
      for (int r = 0; r < 4; ++r)
        obb[quad * 4 + r][h * 64 + d] = f2bf(o4[r]);
    }
    __syncthreads();  // protects kk/vT/qp for next head; obb complete at end
  }

  // ---- attn_proj: O(16x192) @ aw + ab, += into out ----
  bf16x8 ao[6];
#pragma unroll
  for (int ks = 0; ks < 6; ++ks)
    ao[ks] = *(const bf16x8*)(&obb[l15][ks * 32 + quad * 8]);
#pragma unroll
  for (int nl = 0; nl < 3; ++nl) {
    int ntl = wave * 3 + nl;
    const unsigned short* bp = awp + (size_t)ntl * 3072 + lane * 8;
    f32x4 acc = {0.f, 0.f, 0.f, 0.f};
#pragma unroll
    for (int ks = 0; ks < 6; ++ks) {
      bf16x8 bw = *(const bf16x8*)(bp + ks * 512);
      acc = __builtin_amdgcn_mfma_f32_16x16x32_bf16(ao[ks], bw, acc, 0, 0, 0);
    }
    int cc = ntl * 16 + l15;
    float bias = ab[cc];
#pragma unroll
    for (int r = 0; r < 4; ++r) {
      int p = quad * 4 + r;
      int hp = nh * 4 + (p >> 2), wp2 = nw * 4 + (p & 3);
      size_t oi = ((size_t)((b * 128 + hp) * 128 + wp2)) * 192 + cc;
      out[oi] += acc[r] + bias;
    }
  }
}

// ------- Kernel 4: LN2 + MLP via MFMA + residual; in-place on d_out -------
__global__ __launch_bounds__(256) void k4_mlp(
    float* __restrict__ y, const float* __restrict__ g,
    const float* __restrict__ bt, const unsigned short* __restrict__ w1p,
    const float* __restrict__ b1, const unsigned short* __restrict__ w2p,
    const float* __restrict__ b2) {
  __shared__ unsigned short yn[32][196];
  __shared__ unsigned short hls[32][196];
  int tid = threadIdx.x, wave = tid >> 6, lane = tid & 63;
  int l15 = lane & 15, quad = lane >> 4;
  size_t tokbase = (size_t)blockIdx.x * 32;

  for (int j = 0; j < 8; ++j) {
    int tt = wave * 8 + j;
    const float* yr = y + (tokbase + tt) * 192;
    float v0 = yr[lane], v1 = yr[64 + lane], v2 = yr[128 + lane];
    float s = v0 + v1 + v2;
#pragma unroll
    for (int o = 32; o; o >>= 1) s += __shfl_xor(s, o);
    float mean = s * (1.f / 192.f);
    float d0 = v0 - mean, d1 = v1 - mean, d2 = v2 - mean;
    float q = d0 * d0 + d1 * d1 + d2 * d2;
#pragma unroll
    for (int o = 32; o; o >>= 1) q += __shfl_xor(q, o);
    float rstd = rsqrtf(q * (1.f / 192.f) + EPSV);
    yn[tt][lane] = f2bf(d0 * rstd * g[lane] + bt[lane]);
    yn[tt][64 + lane] = f2bf(d1 * rstd * g[64 + lane] + bt[64 + lane]);
    yn[tt][128 + lane] = f2bf(d2 * rstd * g[128 + lane] + bt[128 + lane]);
  }
  __syncthreads();

  f32x4 acc2[3][2];
#pragma unroll
  for (int nl = 0; nl < 3; ++nl)
#pragma unroll
    for (int mt = 0; mt < 2; ++mt) acc2[nl][mt] = (f32x4){0.f, 0.f, 0.f, 0.f};

  for (int c = 0; c < 4; ++c) {
    bf16x8 ar[2][6];
#pragma unroll
    for (int mt = 0; mt < 2; ++mt)
#pragma unroll
      for (int ks = 0; ks < 6; ++ks)
        ar[mt][ks] = *(const bf16x8*)(&yn[mt * 16 + l15][ks * 32 + quad * 8]);
#pragma unroll
    for (int nl = 0; nl < 3; ++nl) {
      int gnt = c * 12 + wave * 3 + nl;
      const unsigned short* bp = w1p + ((size_t)(gnt * 6) * 64 + lane) * 8;
      f32x4 t0 = {0.f, 0.f, 0.f, 0.f}, t1 = {0.f, 0.f, 0.f, 0.f};
#pragma unroll
      for (int ks = 0; ks < 6; ++ks) {
        bf16x8 bw = *(const bf16x8*)(bp + ks * 512);
        t0 = __builtin_amdgcn_mfma_f32_16x16x32_bf16(ar[0][ks], bw, t0, 0, 0, 0);
        t1 = __builtin_amdgcn_mfma_f32_16x16x32_bf16(ar[1][ks], bw, t1, 0, 0, 0);
      }
      int lcol = wave * 48 + nl * 16 + l15;
      float bias = b1[c * 192 + lcol];
#pragma unroll
      for (int r = 0; r < 4; ++r) {
        hls[quad * 4 + r][lcol] = f2bf(fast_gelu(t0[r] + bias));
        hls[16 + quad * 4 + r][lcol] = f2bf(fast_gelu(t1[r] + bias));
      }
    }
    __syncthreads();
    bf16x8 hr[2][6];
#pragma unroll
    for (int mt = 0; mt < 2; ++mt)
#pragma unroll
      for (int ks = 0; ks < 6; ++ks)
        hr[mt][ks] = *(const bf16x8*)(&hls[mt * 16 + l15][ks * 32 + quad * 8]);
#pragma unroll
    for (int nl = 0; nl < 3; ++nl) {
      int nt2 = wave * 3 + nl;
      const unsigned short* bp =
          w2p + ((size_t)((nt2 * 24 + c * 6)) * 64 + lane) * 8;
#pragma unroll
      for (int ks = 0; ks < 6; ++ks) {
        bf16x8 bw = *(const bf16x8*)(bp + ks * 512);
        acc2[nl][0] =
            __builtin_amdgcn_mfma_f32_16x16x32_bf16(hr[0][ks], bw, acc2[nl][0], 0, 0, 0);
        acc2[nl][1] =
            __builtin_amdgcn_mfma_f32_16x16x32_bf16(hr[1][ks], bw, acc2[nl][1], 0, 0, 0);
      }
    }
    __syncthreads();
  }

#pragma unroll
  for (int nl = 0; nl < 3; ++nl) {
    int col = (wave * 3 + nl) * 16 + l15;
    float bias = b2[col];
#pragma unroll
    for (int mt = 0; mt < 2; ++mt) {
#pragma unroll
      for (int r = 0; r < 4; ++r) {
        size_t oi = (tokbase + mt * 16 + quad * 4 + r) * 192 + col;
        y[oi] += acc2[nl][mt][r] + bias;
      }
    }
  }
}

extern "C" void kernel_launch(void* const* d_in, const int* in_sizes, int n_in,
                              void* d_out, int out_size, void* d_ws,
                              size_t ws_size, hipStream_t stream) {
  const float* x = (const float*)d_in[0];
  const float* n1g = (const float*)d_in[1];
  const float* n1b = (const float*)d_in[2];
  const float* pw = (const float*)d_in[3];
  const float* pb = (const float*)d_in[4];
  const float* qw = (const float*)d_in[5];
  const float* qb = (const float*)d_in[6];
  const float* aw = (const float*)d_in[7];
  const float* ab = (const float*)d_in[8];
  const float* n2g = (const float*)d_in[9];
  const float* n2b = (const float*)d_in[10];
  const float* w1 = (const float*)d_in[11];
  const float* b1 = (const float*)d_in[12];
  const float* w2 = (const float*)d_in[13];
  const float* b2 = (const float*)d_in[14];
  float* out = (float*)d_out;

  char* wsb = (char*)d_ws;
  unsigned short* xnb = (unsigned short*)wsb;               // 50,331,648
  unsigned short* qwp = (unsigned short*)(wsb + 50331648);  //    110,592
  unsigned short* awp = (unsigned short*)(wsb + 50442240);  //     73,728
  unsigned short* w1p = (unsigned short*)(wsb + 50515968);  //    294,912
  unsigned short* w2p = (unsigned short*)(wsb + 50810880);  //    294,912
  unsigned short* pwp = (unsigned short*)(wsb + 51105792);  //     36,864

  hipLaunchKernelGGL(k0_pack, dim3(198), dim3(256), 0, stream, qw, aw, w1, w2,
                     pw, qwp, awp, w1p, w2p, pwp);
  hipLaunchKernelGGL(k12_ln_proj, dim3(8192), dim3(256), 0, stream, x, n1g,
                     n1b, pwp, pb, xnb, out);
  hipLaunchKernelGGL(k3_attn, dim3(4096), dim3(256), 0, stream, xnb, qwp, qb,
                     awp, ab, out);
  hipLaunchKernelGGL(k4_mlp, dim3(2048), dim3(256), 0, stream, out, n2g, n2b,
                     w1p, b1, w2p, b2);
}

// Round 5
// 409.842 us; speedup vs baseline: 11.5894x; 1.0419x over previous
//
#include <hip/hip_runtime.h>
#include <hip/hip_bf16.h>
#include <math.h>

#define EPSV 1e-6f

typedef __attribute__((ext_vector_type(8))) short bf16x8;
typedef __attribute__((ext_vector_type(4))) float f32x4;
typedef __attribute__((ext_vector_type(4))) unsigned short u16x4;

__device__ inline float bf2f(unsigned short u) {
  union { unsigned int i; float f; } v;
  v.i = ((unsigned int)u) << 16;
  return v.f;
}
// RNE bf16 round, no NaN path (all values finite here): 3-4 VALU ops
__device__ inline unsigned short f2bf(float f) {
  unsigned int u = __builtin_bit_cast(unsigned int, f);
  u += 0x7FFFu + ((u >> 16) & 1u);
  return (unsigned short)(u >> 16);
}
// tanh-GELU via exp + hw rcp (no div sequence); exact at both tails
__device__ inline float fast_gelu(float v) {
  float u = 1.5957691216057308f * (v + 0.044715f * v * v * v);
  float t = __expf(-u);
  return v * __builtin_amdgcn_rcpf(1.f + t);
}

// ---- Kernel 0: pack all weights into MFMA B-fragment layout (bf16) ----
// B-frag: [ntile][kstep][lane][8], n=ntile*16+(lane&15), k=kstep*32+(lane>>4)*8+j
__global__ __launch_bounds__(256) void k0_pack(
    const float* __restrict__ qw, const float* __restrict__ aw,
    const float* __restrict__ w1, const float* __restrict__ w2,
    const float* __restrict__ pw, unsigned short* __restrict__ qwp,
    unsigned short* __restrict__ awp, unsigned short* __restrict__ w1p,
    unsigned short* __restrict__ w2p, unsigned short* __restrict__ pwp) {
  int idx = blockIdx.x * 256 + threadIdx.x;
  int lane = idx & 63;
  int l15 = lane & 15, quad = lane >> 4;
  if (idx < 6912) {
    int fi = idx >> 6;
    int ntile = fi / 3, kstep = fi - ntile * 3;
    int n = ntile * 16 + l15, k0 = kstep * 32 + quad * 8;
#pragma unroll
    for (int j = 0; j < 8; ++j)
      qwp[(size_t)idx * 8 + j] = f2bf(qw[(size_t)(k0 + j) * 576 + n]);
  } else if (idx < 11520) {
    int i2 = idx - 6912;
    int fi = i2 >> 6;
    int ntile = fi / 6, kstep = fi - ntile * 6;
    int n = ntile * 16 + l15, k0 = kstep * 32 + quad * 8;
#pragma unroll
    for (int j = 0; j < 8; ++j)
      awp[(size_t)i2 * 8 + j] = f2bf(aw[(size_t)(k0 + j) * 192 + n]);
  } else if (idx < 29952) {
    int i3 = idx - 11520;
    int fi = i3 >> 6;
    int ntile = fi / 6, kstep = fi - ntile * 6;
    int n = ntile * 16 + l15, k0 = kstep * 32 + quad * 8;
#pragma unroll
    for (int j = 0; j < 8; ++j)
      w1p[(size_t)i3 * 8 + j] = f2bf(w1[(size_t)(k0 + j) * 768 + n]);
  } else if (idx < 48384) {
    int i4 = idx - 29952;
    int fi = i4 >> 6;
    int ntile = fi / 24, kstep = fi - ntile * 24;
    int n = ntile * 16 + l15, k0 = kstep * 32 + quad * 8;
#pragma unroll
    for (int j = 0; j < 8; ++j)
      w2p[(size_t)i4 * 8 + j] = f2bf(w2[(size_t)(k0 + j) * 192 + n]);
  } else if (idx < 50688) {
    int i5 = idx - 48384;
    int fi = i5 >> 6;
    int ntile = fi / 3, kstep = fi - ntile * 3;
    int n = ntile * 16 + l15, k0 = kstep * 32 + quad * 8;
#pragma unroll
    for (int j = 0; j < 8; ++j)
      pwp[(size_t)i5 * 8 + j] = f2bf(pw[(size_t)(k0 + j) * 192 + n]);
  }
}

// -- Kernel 12: fused LN1 (-> xnb bf16) + proj + maxpool (-> d_out) --------
__global__ __launch_bounds__(256) void k12_ln_proj(
    const float* __restrict__ x, const float* __restrict__ g,
    const float* __restrict__ bta, const unsigned short* __restrict__ pwp,
    const float* __restrict__ pb, unsigned short* __restrict__ xnb,
    float* __restrict__ out) {
  __shared__ unsigned short xs[2][16][104];
  int tid = threadIdx.x, wave = tid >> 6, lane = tid & 63;
  int l15 = lane & 15, quad = lane >> 4;
  int pixbase = blockIdx.x * 8;
  int b = pixbase >> 14;
  int rem = pixbase & 16383;
  int hp = rem >> 7;
  int wp0 = rem & 127;
  int r0 = hp * 2, c0 = wp0 * 2;

#pragma unroll
  for (int j = 0; j < 8; ++j) {
    int tt = wave * 8 + j;
    int rr = tt >> 4, cc = tt & 15;
    size_t tok = (size_t)((b * 256 + r0 + rr) * 256 + c0 + cc);
    const float* xr = x + tok * 96;
    float v0 = xr[lane];
    float v1 = (lane < 32) ? xr[64 + lane] : 0.f;
    float s = v0 + v1;
#pragma unroll
    for (int o = 32; o; o >>= 1) s += __shfl_xor(s, o);
    float mean = s * (1.f / 96.f);
    float d0 = v0 - mean;
    float d1 = (lane < 32) ? (v1 - mean) : 0.f;
    float q = d0 * d0 + d1 * d1;
#pragma unroll
    for (int o = 32; o; o >>= 1) q += __shfl_xor(q, o);
    float rstd = rsqrtf(q * (1.f / 96.f) + EPSV);
    unsigned short* xo = xnb + tok * 96;
    unsigned short e0 = f2bf(d0 * rstd * g[lane] + bta[lane]);
    xo[lane] = e0;
    xs[rr][cc][lane] = e0;
    if (lane < 32) {
      unsigned short e1 = f2bf(d1 * rstd * g[64 + lane] + bta[64 + lane]);
      xo[64 + lane] = e1;
      xs[rr][cc][64 + lane] = e1;
    }
  }
  __syncthreads();

  bf16x8 a[2][3];
#pragma unroll
  for (int mt = 0; mt < 2; ++mt)
#pragma unroll
    for (int ks = 0; ks < 3; ++ks)
      a[mt][ks] = *(const bf16x8*)(&xs[mt][l15][ks * 32 + quad * 8]);

#pragma unroll
  for (int nl = 0; nl < 3; ++nl) {
    int nt = wave * 3 + nl;
    const unsigned short* bp = pwp + ((size_t)(nt * 3) * 64 + lane) * 8;
    f32x4 t0 = {0.f, 0.f, 0.f, 0.f}, t1 = {0.f, 0.f, 0.f, 0.f};
#pragma unroll
    for (int ks = 0; ks < 3; ++ks) {
      bf16x8 bw = *(const bf16x8*)(bp + ks * 512);
      t0 = __builtin_amdgcn_mfma_f32_16x16x32_bf16(a[0][ks], bw, t0, 0, 0, 0);
      t1 = __builtin_amdgcn_mfma_f32_16x16x32_bf16(a[1][ks], bw, t1, 0, 0, 0);
    }
    int c = nt * 16 + l15;
    float bb = pb[c];
    float m0 = fmaxf(fmaxf(t0[0], t0[1]), fmaxf(t1[0], t1[1]));
    float m1 = fmaxf(fmaxf(t0[2], t0[3]), fmaxf(t1[2], t1[3]));
    out[(size_t)(pixbase + quad * 2 + 0) * 192 + c] = m0 + bb;
    out[(size_t)(pixbase + quad * 2 + 1) * 192 + c] = m1 + bb;
  }
}

// --- Kernel 3: windowed attention via MFMA; d_out += attn_proj output ---
__global__ __launch_bounds__(256) void k3_attn(
    const unsigned short* __restrict__ xnb, const unsigned short* __restrict__ qwp,
    const float* __restrict__ qb, const unsigned short* __restrict__ awp,
    const float* __restrict__ ab, float* __restrict__ out) {
  __shared__ unsigned short kk[64][72];    // K [token][d]
  __shared__ unsigned short vT[64][72];    // V^T [d][token]
  __shared__ unsigned short qp[16][72];    // pooled Q [p][d]
  __shared__ float sc[16][72];             // scores
  __shared__ unsigned short pbuf[16][72];  // probs bf16 [p][key]
  __shared__ unsigned short obb[16][200];  // attn out bf16 [p][c]

  int tid = threadIdx.x, wave = tid >> 6, lane = tid & 63;
  int wi = blockIdx.x;
  int b = wi >> 10, nh = (wi >> 5) & 31, nw = wi & 31;
  int grow0 = nh * 8, gcol0 = nw * 8;
  int l15 = lane & 15, quad = lane >> 4;

  bf16x8 areg[4][3];
#pragma unroll
  for (int mt = 0; mt < 4; ++mt) {
    int m = mt * 16 + l15;
    int r = m >> 3, c = m & 7;
    const unsigned short* src =
        xnb + ((size_t)((b * 256 + grow0 + r) * 256 + gcol0 + c)) * 96 + quad * 8;
#pragma unroll
    for (int ks = 0; ks < 3; ++ks)
      areg[mt][ks] = *(const bf16x8*)(src + ks * 32);
  }

  for (int h = 0; h < 3; ++h) {
#pragma unroll
    for (int nl = 0; nl < 3; ++nl) {
      int ln = wave * 3 + nl;
      int type = ln >> 2;  // 0=q,1=k,2=v
      int nt = ln & 3;
      int gnt = type * 12 + h * 4 + nt;
      const unsigned short* bp = qwp + (size_t)gnt * 1536 + lane * 8;
      bf16x8 b0 = *(const bf16x8*)(bp);
      bf16x8 b1 = *(const bf16x8*)(bp + 512);
      bf16x8 b2 = *(const bf16x8*)(bp + 1024);
      int d = nt * 16 + l15;
      float bias = qb[type * 192 + h * 64 + d];
#pragma unroll
      for (int mt = 0; mt < 4; ++mt) {
        f32x4 acc = {0.f, 0.f, 0.f, 0.f};
        acc = __builtin_amdgcn_mfma_f32_16x16x32_bf16(areg[mt][0], b0, acc, 0, 0, 0);
        acc = __builtin_amdgcn_mfma_f32_16x16x32_bf16(areg[mt][1], b1, acc, 0, 0, 0);
        acc = __builtin_amdgcn_mfma_f32_16x16x32_bf16(areg[mt][2], b2, acc, 0, 0, 0);
        if (type == 0) {
          float p0 = fmaxf(acc[0], acc[1]);
          float p1 = fmaxf(acc[2], acc[3]);
          float q0 = fmaxf(p0, __shfl_xor(p0, 32));
          float q1 = fmaxf(p1, __shfl_xor(p1, 32));
          if (quad < 2) {
            int p = mt * 4 + quad * 2;
            qp[p][d] = f2bf(q0 + bias);
            qp[p + 1][d] = f2bf(q1 + bias);
          }
        } else if (type == 1) {
          int t0 = mt * 16 + quad * 4;
#pragma unroll
          for (int r = 0; r < 4; ++r) kk[t0 + r][d] = f2bf(acc[r] + bias);
        } else {
          int t0 = mt * 16 + quad * 4;
          u16x4 pk;
#pragma unroll
          for (int r = 0; r < 4; ++r) pk[r] = f2bf(acc[r] + bias);
          *(u16x4*)(&vT[d][t0]) = pk;
        }
      }
    }
    __syncthreads();

    {
      bf16x8 aq0 = *(const bf16x8*)(&qp[l15][quad * 8]);
      bf16x8 aq1 = *(const bf16x8*)(&qp[l15][32 + quad * 8]);
      int n = wave * 16 + l15;
      bf16x8 bk0 = *(const bf16x8*)(&kk[n][quad * 8]);
      bf16x8 bk1 = *(const bf16x8*)(&kk[n][32 + quad * 8]);
      f32x4 s4 = {0.f, 0.f, 0.f, 0.f};
      s4 = __builtin_amdgcn_mfma_f32_16x16x32_bf16(aq0, bk0, s4, 0, 0, 0);
      s4 = __builtin_amdgcn_mfma_f32_16x16x32_bf16(aq1, bk1, s4, 0, 0, 0);
#pragma unroll
      for (int r = 0; r < 4; ++r) sc[quad * 4 + r][n] = s4[r] * 0.125f;
    }
    __syncthreads();

    {
      int row = tid >> 4, sub = tid & 15;
      float v0 = sc[row][sub], v1 = sc[row][sub + 16];
      float v2 = sc[row][sub + 32], v3 = sc[row][sub + 48];
      float mx = fmaxf(fmaxf(v0, v1), fmaxf(v2, v3));
#pragma unroll
      for (int o = 8; o; o >>= 1) mx = fmaxf(mx, __shfl_xor(mx, o));
      float e0 = __expf(v0 - mx), e1 = __expf(v1 - mx);
      float e2 = __expf(v2 - mx), e3 = __expf(v3 - mx);
      float sm = e0 + e1 + e2 + e3;
#pragma unroll
      for (int o = 8; o; o >>= 1) sm += __shfl_xor(sm, o);
      float inv = __builtin_amdgcn_rcpf(sm);
      pbuf[row][sub] = f2bf(e0 * inv);
      pbuf[row][sub + 16] = f2bf(e1 * inv);
      pbuf[row][sub + 32] = f2bf(e2 * inv);
      pbuf[row][sub + 48] = f2bf(e3 * inv);
    }
    __syncthreads();

    {
      bf16x8 ap0 = *(const bf16x8*)(&pbuf[l15][quad * 8]);
      bf16x8 ap1 = *(const bf16x8*)(&pbuf[l15][32 + quad * 8]);
      int d = wave * 16 + l15;
      bf16x8 bv0 = *(const bf16x8*)(&vT[d][quad * 8]);
      bf16x8 bv1 = *(const bf16x8*)(&vT[d][32 + quad * 8]);
      f32x4 o4 = {0.f, 0.f, 0.f, 0.f};
      o4 = __builtin_amdgcn_mfma_f32_16x16x32_bf16(ap0, bv0, o4, 0, 0, 0);
      o4 = __builtin_amdgcn_mfma_f32_16x16x32_bf16(ap1, bv1, o4, 0, 0, 0);
#pragma unroll
      for (int r = 0; r < 4; ++r)
        obb[quad * 4 + r][h * 64 + d] = f2bf(o4[r]);
    }
    __syncthreads();
  }

  bf16x8 ao[6];
#pragma unroll
  for (int ks = 0; ks < 6; ++ks)
    ao[ks] = *(const bf16x8*)(&obb[l15][ks * 32 + quad * 8]);
#pragma unroll
  for (int nl = 0; nl < 3; ++nl) {
    int ntl = wave * 3 + nl;
    const unsigned short* bp = awp + (size_t)ntl * 3072 + lane * 8;
    f32x4 acc = {0.f, 0.f, 0.f, 0.f};
#pragma unroll
    for (int ks = 0; ks < 6; ++ks) {
      bf16x8 bw = *(const bf16x8*)(bp + ks * 512);
      acc = __builtin_amdgcn_mfma_f32_16x16x32_bf16(ao[ks], bw, acc, 0, 0, 0);
    }
    int cc = ntl * 16 + l15;
    float bias = ab[cc];
#pragma unroll
    for (int r = 0; r < 4; ++r) {
      int p = quad * 4 + r;
      int hp = nh * 4 + (p >> 2), wp2 = nw * 4 + (p & 3);
      size_t oi = ((size_t)((b * 128 + hp) * 128 + wp2)) * 192 + cc;
      out[oi] += acc[r] + bias;
    }
  }
}

// ------- Kernel 4: LN2 + MLP via MFMA + residual; in-place on d_out -------
__global__ __launch_bounds__(256) void k4_mlp(
    float* __restrict__ y, const float* __restrict__ g,
    const float* __restrict__ bt, const unsigned short* __restrict__ w1p,
    const float* __restrict__ b1, const unsigned short* __restrict__ w2p,
    const float* __restrict__ b2) {
  __shared__ unsigned short yn[32][196];
  __shared__ unsigned short hls[32][196];
  int tid = threadIdx.x, wave = tid >> 6, lane = tid & 63;
  int l15 = lane & 15, quad = lane >> 4;
  size_t tokbase = (size_t)blockIdx.x * 32;

  for (int j = 0; j < 8; ++j) {
    int tt = wave * 8 + j;
    const float* yr = y + (tokbase + tt) * 192;
    float v0 = yr[lane], v1 = yr[64 + lane], v2 = yr[128 + lane];
    float s = v0 + v1 + v2;
#pragma unroll
    for (int o = 32; o; o >>= 1) s += __shfl_xor(s, o);
    float mean = s * (1.f / 192.f);
    float d0 = v0 - mean, d1 = v1 - mean, d2 = v2 - mean;
    float q = d0 * d0 + d1 * d1 + d2 * d2;
#pragma unroll
    for (int o = 32; o; o >>= 1) q += __shfl_xor(q, o);
    float rstd = rsqrtf(q * (1.f / 192.f) + EPSV);
    yn[tt][lane] = f2bf(d0 * rstd * g[lane] + bt[lane]);
    yn[tt][64 + lane] = f2bf(d1 * rstd * g[64 + lane] + bt[64 + lane]);
    yn[tt][128 + lane] = f2bf(d2 * rstd * g[128 + lane] + bt[128 + lane]);
  }
  __syncthreads();

  // A-frags for GEMM1 are loop-invariant: hoist (48 VGPRs)
  bf16x8 ar[2][6];
#pragma unroll
  for (int mt = 0; mt < 2; ++mt)
#pragma unroll
    for (int ks = 0; ks < 6; ++ks)
      ar[mt][ks] = *(const bf16x8*)(&yn[mt * 16 + l15][ks * 32 + quad * 8]);

  f32x4 acc2[3][2];
#pragma unroll
  for (int nl = 0; nl < 3; ++nl)
#pragma unroll
    for (int mt = 0; mt < 2; ++mt) acc2[nl][mt] = (f32x4){0.f, 0.f, 0.f, 0.f};

  for (int c = 0; c < 4; ++c) {
#pragma unroll
    for (int nl = 0; nl < 3; ++nl) {
      int gnt = c * 12 + wave * 3 + nl;
      const unsigned short* bp = w1p + ((size_t)(gnt * 6) * 64 + lane) * 8;
      f32x4 t0 = {0.f, 0.f, 0.f, 0.f}, t1 = {0.f, 0.f, 0.f, 0.f};
#pragma unroll
      for (int ks = 0; ks < 6; ++ks) {
        bf16x8 bw = *(const bf16x8*)(bp + ks * 512);
        t0 = __builtin_amdgcn_mfma_f32_16x16x32_bf16(ar[0][ks], bw, t0, 0, 0, 0);
        t1 = __builtin_amdgcn_mfma_f32_16x16x32_bf16(ar[1][ks], bw, t1, 0, 0, 0);
      }
      int lcol = wave * 48 + nl * 16 + l15;
      float bias = b1[c * 192 + lcol];
#pragma unroll
      for (int r = 0; r < 4; ++r) {
        hls[quad * 4 + r][lcol] = f2bf(fast_gelu(t0[r] + bias));
        hls[16 + quad * 4 + r][lcol] = f2bf(fast_gelu(t1[r] + bias));
      }
    }
    __syncthreads();
    bf16x8 hr[2][6];
#pragma unroll
    for (int mt = 0; mt < 2; ++mt)
#pragma unroll
      for (int ks = 0; ks < 6; ++ks)
        hr[mt][ks] = *(const bf16x8*)(&hls[mt * 16 + l15][ks * 32 + quad * 8]);
#pragma unroll
    for (int nl = 0; nl < 3; ++nl) {
      int nt2 = wave * 3 + nl;
      const unsigned short* bp =
          w2p + ((size_t)((nt2 * 24 + c * 6)) * 64 + lane) * 8;
#pragma unroll
      for (int ks = 0; ks < 6; ++ks) {
        bf16x8 bw = *(const bf16x8*)(bp + ks * 512);
        acc2[nl][0] =
            __builtin_amdgcn_mfma_f32_16x16x32_bf16(hr[0][ks], bw, acc2[nl][0], 0, 0, 0);
        acc2[nl][1] =
            __builtin_amdgcn_mfma_f32_16x16x32_bf16(hr[1][ks], bw, acc2[nl][1], 0, 0, 0);
      }
    }
    __syncthreads();
  }

#pragma unroll
  for (int nl = 0; nl < 3; ++nl) {
    int col = (wave * 3 + nl) * 16 + l15;
    float bias = b2[col];
#pragma unroll
    for (int mt = 0; mt < 2; ++mt) {
#pragma unroll
      for (int r = 0; r < 4; ++r) {
        size_t oi = (tokbase + mt * 16 + quad * 4 + r) * 192 + col;
        y[oi] += acc2[nl][mt][r] + bias;
      }
    }
  }
}

extern "C" void kernel_launch(void* const* d_in, const int* in_sizes, int n_in,
                              void* d_out, int out_size, void* d_ws,
                              size_t ws_size, hipStream_t stream) {
  const float* x = (const float*)d_in[0];
  const float* n1g = (const float*)d_in[1];
  const float* n1b = (const float*)d_in[2];
  const float* pw = (const float*)d_in[3];
  const float* pb = (const float*)d_in[4];
  const float* qw = (const float*)d_in[5];
  const float* qb = (const float*)d_in[6];
  const float* aw = (const float*)d_in[7];
  const float* ab = (const float*)d_in[8];
  const float* n2g = (const float*)d_in[9];
  const float* n2b = (const float*)d_in[10];
  const float* w1 = (const float*)d_in[11];
  const float* b1 = (const float*)d_in[12];
  const float* w2 = (const float*)d_in[13];
  const float* b2 = (const float*)d_in[14];
  float* out = (float*)d_out;

  char* wsb = (char*)d_ws;
  unsigned short* xnb = (unsigned short*)wsb;               // 50,331,648
  unsigned short* qwp = (unsigned short*)(wsb + 50331648);  //    110,592
  unsigned short* awp = (unsigned short*)(wsb + 50442240);  //     73,728
  unsigned short* w1p = (unsigned short*)(wsb + 50515968);  //    294,912
  unsigned short* w2p = (unsigned short*)(wsb + 50810880);  //    294,912
  unsigned short* pwp = (unsigned short*)(wsb + 51105792);  //     36,864

  hipLaunchKernelGGL(k0_pack, dim3(198), dim3(256), 0, stream, qw, aw, w1, w2,
                     pw, qwp, awp, w1p, w2p, pwp);
  hipLaunchKernelGGL(k12_ln_proj, dim3(8192), dim3(256), 0, stream, x, n1g,
                     n1b, pwp, pb, xnb, out);
  hipLaunchKernelGGL(k3_attn, dim3(4096), dim3(256), 0, stream, xnb, qwp, qb,
                     awp, ab, out);
  hipLaunchKernelGGL(k4_mlp, dim3(2048), dim3(256), 0, stream, out, n2g, n2b,
                     w1p, b1, w2p, b2);
}

// Round 6
// 390.067 us; speedup vs baseline: 12.1769x; 1.0507x over previous
//
#include <hip/hip_runtime.h>
#include <hip/hip_bf16.h>
#include <math.h>

#define EPSV 1e-6f

typedef __attribute__((ext_vector_type(8))) short bf16x8;
typedef __attribute__((ext_vector_type(4))) float f32x4;
typedef __attribute__((ext_vector_type(4))) unsigned short u16x4;

__device__ inline float bf2f(unsigned short u) {
  union { unsigned int i; float f; } v;
  v.i = ((unsigned int)u) << 16;
  return v.f;
}
// RNE bf16 round, no NaN path (all values finite here)
__device__ inline unsigned short f2bf(float f) {
  unsigned int u = __builtin_bit_cast(unsigned int, f);
  u += 0x7FFFu + ((u >> 16) & 1u);
  return (unsigned short)(u >> 16);
}
// tanh-GELU via exp + hw rcp (no div sequence)
__device__ inline float fast_gelu(float v) {
  float u = 1.5957691216057308f * (v + 0.044715f * v * v * v);
  float t = __expf(-u);
  return v * __builtin_amdgcn_rcpf(1.f + t);
}

// ---- Kernel 0: pack all weights into MFMA B-fragment layout (bf16) ----
// B-frag: [ntile][kstep][lane][8], n=ntile*16+(lane&15), k=kstep*32+(lane>>4)*8+j
__global__ __launch_bounds__(256) void k0_pack(
    const float* __restrict__ qw, const float* __restrict__ aw,
    const float* __restrict__ w1, const float* __restrict__ w2,
    const float* __restrict__ pw, unsigned short* __restrict__ qwp,
    unsigned short* __restrict__ awp, unsigned short* __restrict__ w1p,
    unsigned short* __restrict__ w2p, unsigned short* __restrict__ pwp) {
  int idx = blockIdx.x * 256 + threadIdx.x;
  int lane = idx & 63;
  int l15 = lane & 15, quad = lane >> 4;
  if (idx < 6912) {
    int fi = idx >> 6;
    int ntile = fi / 3, kstep = fi - ntile * 3;
    int n = ntile * 16 + l15, k0 = kstep * 32 + quad * 8;
#pragma unroll
    for (int j = 0; j < 8; ++j)
      qwp[(size_t)idx * 8 + j] = f2bf(qw[(size_t)(k0 + j) * 576 + n]);
  } else if (idx < 11520) {
    int i2 = idx - 6912;
    int fi = i2 >> 6;
    int ntile = fi / 6, kstep = fi - ntile * 6;
    int n = ntile * 16 + l15, k0 = kstep * 32 + quad * 8;
#pragma unroll
    for (int j = 0; j < 8; ++j)
      awp[(size_t)i2 * 8 + j] = f2bf(aw[(size_t)(k0 + j) * 192 + n]);
  } else if (idx < 29952) {
    int i3 = idx - 11520;
    int fi = i3 >> 6;
    int ntile = fi / 6, kstep = fi - ntile * 6;
    int n = ntile * 16 + l15, k0 = kstep * 32 + quad * 8;
#pragma unroll
    for (int j = 0; j < 8; ++j)
      w1p[(size_t)i3 * 8 + j] = f2bf(w1[(size_t)(k0 + j) * 768 + n]);
  } else if (idx < 48384) {
    int i4 = idx - 29952;
    int fi = i4 >> 6;
    int ntile = fi / 24, kstep = fi - ntile * 24;
    int n = ntile * 16 + l15, k0 = kstep * 32 + quad * 8;
#pragma unroll
    for (int j = 0; j < 8; ++j)
      w2p[(size_t)i4 * 8 + j] = f2bf(w2[(size_t)(k0 + j) * 192 + n]);
  } else if (idx < 50688) {
    int i5 = idx - 48384;
    int fi = i5 >> 6;
    int ntile = fi / 3, kstep = fi - ntile * 3;
    int n = ntile * 16 + l15, k0 = kstep * 32 + quad * 8;
#pragma unroll
    for (int j = 0; j < 8; ++j)
      pwp[(size_t)i5 * 8 + j] = f2bf(pw[(size_t)(k0 + j) * 192 + n]);
  }
}

// -- Kernel 12: fused LN1 (-> xnb bf16) + proj + maxpool (-> d_out) --------
// LN: 8 threads per token, 3x float4 loads each, 3-deep shfl reductions.
__global__ __launch_bounds__(256) void k12_ln_proj(
    const float* __restrict__ x, const float* __restrict__ g,
    const float* __restrict__ bta, const unsigned short* __restrict__ pwp,
    const float* __restrict__ pb, unsigned short* __restrict__ xnb,
    float* __restrict__ out) {
  __shared__ unsigned short xs[2][16][104];
  int tid = threadIdx.x, wave = tid >> 6, lane = tid & 63;
  int l15 = lane & 15, quad = lane >> 4;
  int pixbase = blockIdx.x * 8;
  int b = pixbase >> 14;
  int rem = pixbase & 16383;
  int hp = rem >> 7;
  int wp0 = rem & 127;
  int r0 = hp * 2, c0 = wp0 * 2;

  // ---- LN: token tt (0..31) handled by 8 threads (sub 0..7) ----
  int tt = tid >> 3, sub = tid & 7;
  int rr = tt >> 4, cc = tt & 15;
  size_t tok = (size_t)((b * 256 + r0 + rr) * 256 + c0 + cc);
  const f32x4* xr4 = (const f32x4*)(x + tok * 96 + sub * 12);
  f32x4 v[3];
  v[0] = xr4[0]; v[1] = xr4[1]; v[2] = xr4[2];
  float s = 0.f;
#pragma unroll
  for (int i = 0; i < 3; ++i)
#pragma unroll
    for (int j = 0; j < 4; ++j) s += v[i][j];
#pragma unroll
  for (int o = 1; o < 8; o <<= 1) s += __shfl_xor(s, o);
  float mean = s * (1.f / 96.f);
  float q = 0.f;
#pragma unroll
  for (int i = 0; i < 3; ++i)
#pragma unroll
    for (int j = 0; j < 4; ++j) {
      float d = v[i][j] - mean;
      q += d * d;
    }
#pragma unroll
  for (int o = 1; o < 8; o <<= 1) q += __shfl_xor(q, o);
  float rstd = rsqrtf(q * (1.f / 96.f) + EPSV);
  const f32x4* g4 = (const f32x4*)(g + sub * 12);
  const f32x4* b4 = (const f32x4*)(bta + sub * 12);
  u16x4 o16[3];
#pragma unroll
  for (int i = 0; i < 3; ++i) {
    f32x4 gg = g4[i], bb = b4[i];
#pragma unroll
    for (int j = 0; j < 4; ++j)
      o16[i][j] = f2bf((v[i][j] - mean) * rstd * gg[j] + bb[j]);
  }
  u16x4* xo = (u16x4*)(xnb + tok * 96 + sub * 12);
  xo[0] = o16[0]; xo[1] = o16[1]; xo[2] = o16[2];
  u16x4* xsp = (u16x4*)(&xs[rr][cc][sub * 12]);
  xsp[0] = o16[0]; xsp[1] = o16[1]; xsp[2] = o16[2];
  __syncthreads();

  // ---- proj + maxpool via MFMA (A row m = column-token) ----
  bf16x8 a[2][3];
#pragma unroll
  for (int mt = 0; mt < 2; ++mt)
#pragma unroll
    for (int ks = 0; ks < 3; ++ks)
      a[mt][ks] = *(const bf16x8*)(&xs[mt][l15][ks * 32 + quad * 8]);

#pragma unroll
  for (int nl = 0; nl < 3; ++nl) {
    int nt = wave * 3 + nl;
    const unsigned short* bp = pwp + ((size_t)(nt * 3) * 64 + lane) * 8;
    f32x4 t0 = {0.f, 0.f, 0.f, 0.f}, t1 = {0.f, 0.f, 0.f, 0.f};
#pragma unroll
    for (int ks = 0; ks < 3; ++ks) {
      bf16x8 bw = *(const bf16x8*)(bp + ks * 512);
      t0 = __builtin_amdgcn_mfma_f32_16x16x32_bf16(a[0][ks], bw, t0, 0, 0, 0);
      t1 = __builtin_amdgcn_mfma_f32_16x16x32_bf16(a[1][ks], bw, t1, 0, 0, 0);
    }
    int c = nt * 16 + l15;
    float bb = pb[c];
    float m0 = fmaxf(fmaxf(t0[0], t0[1]), fmaxf(t1[0], t1[1]));
    float m1 = fmaxf(fmaxf(t0[2], t0[3]), fmaxf(t1[2], t1[3]));
    out[(size_t)(pixbase + quad * 2 + 0) * 192 + c] = m0 + bb;
    out[(size_t)(pixbase + quad * 2 + 1) * 192 + c] = m1 + bb;
  }
}

// --- Kernel 3: windowed attention via MFMA; 3 barriers total ---
// Phase 1: all heads' qkv staged at once; wave h computes its own head's
// pooled Q into a wave-private buffer. Phase 2: wave h owns head h's
// S/softmax(in-register)/PV. attn-out reuses kk's LDS.
__global__ __launch_bounds__(256) void k3_attn(
    const unsigned short* __restrict__ xnb, const unsigned short* __restrict__ qwp,
    const float* __restrict__ qb, const unsigned short* __restrict__ awp,
    const float* __restrict__ ab, float* __restrict__ out) {
  __shared__ unsigned short kk[64][200];     // K [token][dglob]; rows 0..15 reused as obb[16][200]
  __shared__ unsigned short vT[192][72];     // V^T [dglob][token]
  __shared__ unsigned short wbuf[4][16][72]; // per-wave: pooled Q, then P

  int tid = threadIdx.x, wave = tid >> 6, lane = tid & 63;
  int wi = blockIdx.x;
  int b = wi >> 10, nh = (wi >> 5) & 31, nw = wi & 31;
  int grow0 = nh * 8, gcol0 = nw * 8;
  int l15 = lane & 15, quad = lane >> 4;

  // A-frags (xw 64x96) straight from global
  bf16x8 areg[4][3];
#pragma unroll
  for (int mt = 0; mt < 4; ++mt) {
    int m = mt * 16 + l15;
    int r = m >> 3, c = m & 7;
    const unsigned short* src =
        xnb + ((size_t)((b * 256 + grow0 + r) * 256 + gcol0 + c)) * 96 + quad * 8;
#pragma unroll
    for (int ks = 0; ks < 3; ++ks)
      areg[mt][ks] = *(const bf16x8*)(src + ks * 32);
  }

  // ---- Phase 1: qkv GEMM, 9 ntile-jobs per wave ----
  // wave<3: 4 Q-jobs of own head + 5 K/V jobs; wave 3: 9 K/V jobs.
#pragma unroll
  for (int aj = 0; aj < 9; ++aj) {
    int type, hh, nt;
    if (wave < 3) {
      if (aj < 4) { type = 0; hh = wave; nt = aj; }
      else { int kv = wave * 5 + (aj - 4); type = 1 + kv / 12; int t2 = kv % 12; hh = t2 >> 2; nt = t2 & 3; }
    } else {
      int kv = 15 + aj; type = 1 + kv / 12; int t2 = kv % 12; hh = t2 >> 2; nt = t2 & 3;
    }
    int gnt = type * 12 + hh * 4 + nt;
    const unsigned short* bp = qwp + (size_t)gnt * 1536 + lane * 8;
    bf16x8 b0 = *(const bf16x8*)(bp);
    bf16x8 b1 = *(const bf16x8*)(bp + 512);
    bf16x8 b2 = *(const bf16x8*)(bp + 1024);
    int dloc = nt * 16 + l15;
    int dglob = hh * 64 + dloc;
    float bias = qb[type * 192 + dglob];
#pragma unroll
    for (int mt = 0; mt < 4; ++mt) {
      f32x4 acc = {0.f, 0.f, 0.f, 0.f};
      acc = __builtin_amdgcn_mfma_f32_16x16x32_bf16(areg[mt][0], b0, acc, 0, 0, 0);
      acc = __builtin_amdgcn_mfma_f32_16x16x32_bf16(areg[mt][1], b1, acc, 0, 0, 0);
      acc = __builtin_amdgcn_mfma_f32_16x16x32_bf16(areg[mt][2], b2, acc, 0, 0, 0);
      if (type == 0) {
        float p0 = fmaxf(acc[0], acc[1]);
        float p1 = fmaxf(acc[2], acc[3]);
        float q0 = fmaxf(p0, __shfl_xor(p0, 32));
        float q1 = fmaxf(p1, __shfl_xor(p1, 32));
        if (quad < 2) {
          int p = mt * 4 + quad * 2;
          wbuf[wave][p][dloc] = f2bf(q0 + bias);      // pooled Q, wave-private
          wbuf[wave][p + 1][dloc] = f2bf(q1 + bias);
        }
      } else if (type == 1) {
        int t0 = mt * 16 + quad * 4;
#pragma unroll
        for (int r = 0; r < 4; ++r) kk[t0 + r][dglob] = f2bf(acc[r] + bias);
      } else {
        int t0 = mt * 16 + quad * 4;
        u16x4 pk;
#pragma unroll
        for (int r = 0; r < 4; ++r) pk[r] = f2bf(acc[r] + bias);
        *(u16x4*)(&vT[dglob][t0]) = pk;
      }
    }
  }
  __syncthreads();  // B1: kk/vT visible to all waves

  // ---- Phase 2: wave h owns head h ----
  f32x4 o4[4];
  if (wave < 3) {
    int h = wave;
    bf16x8 aq0 = *(const bf16x8*)(&wbuf[wave][l15][quad * 8]);
    bf16x8 aq1 = *(const bf16x8*)(&wbuf[wave][l15][32 + quad * 8]);
    f32x4 s4[4];
#pragma unroll
    for (int kt = 0; kt < 4; ++kt) {
      bf16x8 bk0 = *(const bf16x8*)(&kk[kt * 16 + l15][h * 64 + quad * 8]);
      bf16x8 bk1 = *(const bf16x8*)(&kk[kt * 16 + l15][h * 64 + 32 + quad * 8]);
      f32x4 s = {0.f, 0.f, 0.f, 0.f};
      s = __builtin_amdgcn_mfma_f32_16x16x32_bf16(aq0, bk0, s, 0, 0, 0);
      s = __builtin_amdgcn_mfma_f32_16x16x32_bf16(aq1, bk1, s, 0, 0, 0);
      s4[kt] = s;
    }
    // in-register softmax over 64 keys (4 regs x 16 l15-lanes per row)
    float ps[4][4];
#pragma unroll
    for (int r = 0; r < 4; ++r) {
      float m = fmaxf(fmaxf(s4[0][r], s4[1][r]), fmaxf(s4[2][r], s4[3][r]));
#pragma unroll
      for (int o = 8; o; o >>= 1) m = fmaxf(m, __shfl_xor(m, o));
      float sm = 0.f;
#pragma unroll
      for (int kt = 0; kt < 4; ++kt) {
        float e = __expf((s4[kt][r] - m) * 0.125f);
        ps[kt][r] = e;
        sm += e;
      }
#pragma unroll
      for (int o = 8; o; o >>= 1) sm += __shfl_xor(sm, o);
      float inv = __builtin_amdgcn_rcpf(sm);
#pragma unroll
      for (int kt = 0; kt < 4; ++kt) ps[kt][r] *= inv;
    }
    // P -> A-layout via wave-private LDS (overwrites pooled Q; aq in regs)
#pragma unroll
    for (int kt = 0; kt < 4; ++kt)
#pragma unroll
      for (int r = 0; r < 4; ++r)
        wbuf[wave][quad * 4 + r][kt * 16 + l15] = f2bf(ps[kt][r]);
    bf16x8 ap0 = *(const bf16x8*)(&wbuf[wave][l15][quad * 8]);
    bf16x8 ap1 = *(const bf16x8*)(&wbuf[wave][l15][32 + quad * 8]);
#pragma unroll
    for (int dt = 0; dt < 4; ++dt) {
      bf16x8 bv0 = *(const bf16x8*)(&vT[h * 64 + dt * 16 + l15][quad * 8]);
      bf16x8 bv1 = *(const bf16x8*)(&vT[h * 64 + dt * 16 + l15][32 + quad * 8]);
      f32x4 o = {0.f, 0.f, 0.f, 0.f};
      o = __builtin_amdgcn_mfma_f32_16x16x32_bf16(ap0, bv0, o, 0, 0, 0);
      o = __builtin_amdgcn_mfma_f32_16x16x32_bf16(ap1, bv1, o, 0, 0, 0);
      o4[dt] = o;
    }
  }
  __syncthreads();  // B2: all kk/vT reads done -> safe to overwrite kk with obb

  if (wave < 3) {
    int h = wave;
#pragma unroll
    for (int dt = 0; dt < 4; ++dt)
#pragma unroll
      for (int r = 0; r < 4; ++r)
        kk[quad * 4 + r][h * 64 + dt * 16 + l15] = f2bf(o4[dt][r]);  // obb
  }
  __syncthreads();  // B3: obb readable

  // ---- attn_proj: O(16x192) @ aw + ab, += into out ----
  bf16x8 ao[6];
#pragma unroll
  for (int ks = 0; ks < 6; ++ks)
    ao[ks] = *(const bf16x8*)(&kk[l15][ks * 32 + quad * 8]);
#pragma unroll
  for (int nl = 0; nl < 3; ++nl) {
    int ntl = wave * 3 + nl;
    const unsigned short* bp = awp + (size_t)ntl * 3072 + lane * 8;
    f32x4 acc = {0.f, 0.f, 0.f, 0.f};
#pragma unroll
    for (int ks = 0; ks < 6; ++ks) {
      bf16x8 bw = *(const bf16x8*)(bp + ks * 512);
      acc = __builtin_amdgcn_mfma_f32_16x16x32_bf16(ao[ks], bw, acc, 0, 0, 0);
    }
    int cc = ntl * 16 + l15;
    float bias = ab[cc];
#pragma unroll
    for (int r = 0; r < 4; ++r) {
      int p = quad * 4 + r;
      int hp = nh * 4 + (p >> 2), wp2 = nw * 4 + (p & 3);
      size_t oi = ((size_t)((b * 128 + hp) * 128 + wp2)) * 192 + cc;
      out[oi] += acc[r] + bias;
    }
  }
}

// ------- Kernel 4: LN2 + MLP via MFMA + residual; in-place on d_out -------
__global__ __launch_bounds__(256) void k4_mlp(
    float* __restrict__ y, const float* __restrict__ g,
    const float* __restrict__ bt, const unsigned short* __restrict__ w1p,
    const float* __restrict__ b1, const unsigned short* __restrict__ w2p,
    const float* __restrict__ b2) {
  __shared__ unsigned short yn[32][196];
  __shared__ unsigned short hls[32][196];
  int tid = threadIdx.x, wave = tid >> 6, lane = tid & 63;
  int l15 = lane & 15, quad = lane >> 4;
  size_t tokbase = (size_t)blockIdx.x * 32;

  for (int j = 0; j < 8; ++j) {
    int tt = wave * 8 + j;
    const float* yr = y + (tokbase + tt) * 192;
    float v0 = yr[lane], v1 = yr[64 + lane], v2 = yr[128 + lane];
    float s = v0 + v1 + v2;
#pragma unroll
    for (int o = 32; o; o >>= 1) s += __shfl_xor(s, o);
    float mean = s * (1.f / 192.f);
    float d0 = v0 - mean, d1 = v1 - mean, d2 = v2 - mean;
    float q = d0 * d0 + d1 * d1 + d2 * d2;
#pragma unroll
    for (int o = 32; o; o >>= 1) q += __shfl_xor(q, o);
    float rstd = rsqrtf(q * (1.f / 192.f) + EPSV);
    yn[tt][lane] = f2bf(d0 * rstd * g[lane] + bt[lane]);
    yn[tt][64 + lane] = f2bf(d1 * rstd * g[64 + lane] + bt[64 + lane]);
    yn[tt][128 + lane] = f2bf(d2 * rstd * g[128 + lane] + bt[128 + lane]);
  }
  __syncthreads();

  bf16x8 ar[2][6];
#pragma unroll
  for (int mt = 0; mt < 2; ++mt)
#pragma unroll
    for (int ks = 0; ks < 6; ++ks)
      ar[mt][ks] = *(const bf16x8*)(&yn[mt * 16 + l15][ks * 32 + quad * 8]);

  f32x4 acc2[3][2];
#pragma unroll
  for (int nl = 0; nl < 3; ++nl)
#pragma unroll
    for (int mt = 0; mt < 2; ++mt) acc2[nl][mt] = (f32x4){0.f, 0.f, 0.f, 0.f};

  for (int c = 0; c < 4; ++c) {
#pragma unroll
    for (int nl = 0; nl < 3; ++nl) {
      int gnt = c * 12 + wave * 3 + nl;
      const unsigned short* bp = w1p + ((size_t)(gnt * 6) * 64 + lane) * 8;
      f32x4 t0 = {0.f, 0.f, 0.f, 0.f}, t1 = {0.f, 0.f, 0.f, 0.f};
#pragma unroll
      for (int ks = 0; ks < 6; ++ks) {
        bf16x8 bw = *(const bf16x8*)(bp + ks * 512);
        t0 = __builtin_amdgcn_mfma_f32_16x16x32_bf16(ar[0][ks], bw, t0, 0, 0, 0);
        t1 = __builtin_amdgcn_mfma_f32_16x16x32_bf16(ar[1][ks], bw, t1, 0, 0, 0);
      }
      int lcol = wave * 48 + nl * 16 + l15;
      float bias = b1[c * 192 + lcol];
#pragma unroll
      for (int r = 0; r < 4; ++r) {
        hls[quad * 4 + r][lcol] = f2bf(fast_gelu(t0[r] + bias));
        hls[16 + quad * 4 + r][lcol] = f2bf(fast_gelu(t1[r] + bias));
      }
    }
    __syncthreads();
    bf16x8 hr[2][6];
#pragma unroll
    for (int mt = 0; mt < 2; ++mt)
#pragma unroll
      for (int ks = 0; ks < 6; ++ks)
        hr[mt][ks] = *(const bf16x8*)(&hls[mt * 16 + l15][ks * 32 + quad * 8]);
#pragma unroll
    for (int nl = 0; nl < 3; ++nl) {
      int nt2 = wave * 3 + nl;
      const unsigned short* bp =
          w2p + ((size_t)((nt2 * 24 + c * 6)) * 64 + lane) * 8;
#pragma unroll
      for (int ks = 0; ks < 6; ++ks) {
        bf16x8 bw = *(const bf16x8*)(bp + ks * 512);
        acc2[nl][0] =
            __builtin_amdgcn_mfma_f32_16x16x32_bf16(hr[0][ks], bw, acc2[nl][0], 0, 0, 0);
        acc2[nl][1] =
            __builtin_amdgcn_mfma_f32_16x16x32_bf16(hr[1][ks], bw, acc2[nl][1], 0, 0, 0);
      }
    }
    __syncthreads();
  }

#pragma unroll
  for (int nl = 0; nl < 3; ++nl) {
    int col = (wave * 3 + nl) * 16 + l15;
    float bias = b2[col];
#pragma unroll
    for (int mt = 0; mt < 2; ++mt) {
#pragma unroll
      for (int r = 0; r < 4; ++r) {
        size_t oi = (tokbase + mt * 16 + quad * 4 + r) * 192 + col;
        y[oi] += acc2[nl][mt][r] + bias;
      }
    }
  }
}

extern "C" void kernel_launch(void* const* d_in, const int* in_sizes, int n_in,
                              void* d_out, int out_size, void* d_ws,
                              size_t ws_size, hipStream_t stream) {
  const float* x = (const float*)d_in[0];
  const float* n1g = (const float*)d_in[1];
  const float* n1b = (const float*)d_in[2];
  const float* pw = (const float*)d_in[3];
  const float* pb = (const float*)d_in[4];
  const float* qw = (const float*)d_in[5];
  const float* qb = (const float*)d_in[6];
  const float* aw = (const float*)d_in[7];
  const float* ab = (const float*)d_in[8];
  const float* n2g = (const float*)d_in[9];
  const float* n2b = (const float*)d_in[10];
  const float* w1 = (const float*)d_in[11];
  const float* b1 = (const float*)d_in[12];
  const float* w2 = (const float*)d_in[13];
  const float* b2 = (const float*)d_in[14];
  float* out = (float*)d_out;

  char* wsb = (char*)d_ws;
  unsigned short* xnb = (unsigned short*)wsb;               // 50,331,648
  unsigned short* qwp = (unsigned short*)(wsb + 50331648);  //    110,592
  unsigned short* awp = (unsigned short*)(wsb + 50442240);  //     73,728
  unsigned short* w1p = (unsigned short*)(wsb + 50515968);  //    294,912
  unsigned short* w2p = (unsigned short*)(wsb + 50810880);  //    294,912
  unsigned short* pwp = (unsigned short*)(wsb + 51105792);  //     36,864

  hipLaunchKernelGGL(k0_pack, dim3(198), dim3(256), 0, stream, qw, aw, w1, w2,
                     pw, qwp, awp, w1p, w2p, pwp);
  hipLaunchKernelGGL(k12_ln_proj, dim3(8192), dim3(256), 0, stream, x, n1g,
                     n1b, pwp, pb, xnb, out);
  hipLaunchKernelGGL(k3_attn, dim3(4096), dim3(256), 0, stream, xnb, qwp, qb,
                     awp, ab, out);
  hipLaunchKernelGGL(k4_mlp, dim3(2048), dim3(256), 0, stream, out, n2g, n2b,
                     w1p, b1, w2p, b2);
}